// Round 14
// baseline (749.703 us; speedup 1.0000x reference)
//
#include <hip/hip_runtime.h>
#include <math.h>
#include <cstddef>

#define B_ 16
#define T_ 256
#define D_ 128
#define H_ 128
#define L_ 4
#define G_ 512          // 4*H
#define NC_ 10
#define EPS_ 1e-5f
#define C_ 16           // pipeline chunk (timesteps per flag)
#define NCHUNK_ (T_ / C_)

// legacy padded layout (px rider): rows of 144; HOFF for 32-stride pads
#define HROW_ 144
#define HOFF(k) ((k) + (((k) >> 5) << 2))
// new padded layout (rec/producer): rows of 160; +4 floats per 16 -> the 8
// s-slice base addresses (s*80B) hit disjoint bank-quads
#define HROWP_ 160
#define HOFFP(k) ((k) + (((k) >> 4) << 2))

typedef float f4v __attribute__((ext_vector_type(4)));

// 4 x global_load_dwordx4 -> 16 floats resident (compiler cannot remat asm)
#define LOAD_W4(w, base)                                                   \
    asm volatile(                                                          \
        "global_load_dwordx4 %0, %4, off\n\t"                             \
        "global_load_dwordx4 %1, %4, off offset:16\n\t"                   \
        "global_load_dwordx4 %2, %4, off offset:32\n\t"                   \
        "global_load_dwordx4 %3, %4, off offset:48\n\t"                   \
        "s_waitcnt vmcnt(0)"                                               \
        : "=&v"(w[0]), "=&v"(w[1]), "=&v"(w[2]), "=&v"(w[3])               \
        : "v"(base)                                                        \
        : "memory")

// 8 x global_load_dwordx4 (px rider keeps the old shape)
#define LOAD_W8(w, base)                                                   \
    asm volatile(                                                          \
        "global_load_dwordx4 %0, %8, off\n\t"                             \
        "global_load_dwordx4 %1, %8, off offset:16\n\t"                   \
        "global_load_dwordx4 %2, %8, off offset:32\n\t"                   \
        "global_load_dwordx4 %3, %8, off offset:48\n\t"                   \
        "global_load_dwordx4 %4, %8, off offset:64\n\t"                   \
        "global_load_dwordx4 %5, %8, off offset:80\n\t"                   \
        "global_load_dwordx4 %6, %8, off offset:96\n\t"                   \
        "global_load_dwordx4 %7, %8, off offset:112\n\t"                  \
        "s_waitcnt vmcnt(0)"                                               \
        : "=&v"(w[0]), "=&v"(w[1]), "=&v"(w[2]), "=&v"(w[3]),              \
          "=&v"(w[4]), "=&v"(w[5]), "=&v"(w[6]), "=&v"(w[7])               \
        : "v"(base)                                                        \
        : "memory")

// 16-k partial dot (params avoid x/y/z/w tokens)
#define DOT16R(dst_, warr_, hvarr_)                                        \
    {                                                                      \
        float d0_ = 0.f, d1_ = 0.f;                                        \
        _Pragma("unroll")                                                  \
        for (int u_ = 0; u_ < 4; u_++) {                                   \
            d0_ = fmaf(warr_[u_].x, hvarr_[u_].x, d0_);                    \
            d1_ = fmaf(warr_[u_].y, hvarr_[u_].y, d1_);                    \
            d0_ = fmaf(warr_[u_].z, hvarr_[u_].z, d0_);                    \
            d1_ = fmaf(warr_[u_].w, hvarr_[u_].w, d1_);                    \
        }                                                                  \
        dst_ = d0_ + d1_;                                                  \
    }

#define DOT32R(dst_, warr_, hvarr_)                                        \
    {                                                                      \
        float d0_ = 0.f, d1_ = 0.f;                                        \
        _Pragma("unroll")                                                  \
        for (int j_ = 0; j_ < 8; j_++) {                                   \
            d0_ = fmaf(warr_[j_].x, hvarr_[j_].x, d0_);                    \
            d1_ = fmaf(warr_[j_].y, hvarr_[j_].y, d1_);                    \
            d0_ = fmaf(warr_[j_].z, hvarr_[j_].z, d0_);                    \
            d1_ = fmaf(warr_[j_].w, hvarr_[j_].w, d1_);                    \
        }                                                                  \
        dst_ = d0_ + d1_;                                                  \
    }

// ---------------- device helpers ----------------
__device__ __forceinline__ float sigmoid_(float x) {
    x = fminf(fmaxf(x, -30.f), 30.f);
    return 1.f / (1.f + __expf(-x));
}
__device__ __forceinline__ float tanh_(float x) {
    float ax = fminf(fabsf(x), 15.f);
    float e = __expf(2.f * ax);
    float t = 1.f - 2.f / (e + 1.f);
    return copysignf(t, x);
}
__device__ __forceinline__ void wait_ge_(int* p, int v) {
    if (__hip_atomic_load(p, __ATOMIC_RELAXED, __HIP_MEMORY_SCOPE_AGENT) < v) {
        do { __builtin_amdgcn_s_sleep(1); }
        while (__hip_atomic_load(p, __ATOMIC_RELAXED, __HIP_MEMORY_SCOPE_AGENT) < v);
    }
    (void)__hip_atomic_load(p, __ATOMIC_ACQUIRE, __HIP_MEMORY_SCOPE_AGENT);
}

// ---------------- head: per-(b,strip) partial stats (256 WGs) ----------------
__global__ __launch_bounds__(512) void stats_bd(const float* __restrict__ x,
                                                float* __restrict__ psum,
                                                float* __restrict__ psq) {
    int blk = blockIdx.x;                 // b*16 + strip
    int b = blk >> 4, strip = blk & 15;
    int tid = threadIdx.x;
    int d = tid & 127, r = tid >> 7;
    const float* xb = x + (size_t)b * T_ * D_ + (size_t)strip * 16 * D_;
    float s = 0.f, q = 0.f;
    for (int t = r; t < 16; t += 4) {
        float v = xb[t * D_ + d];
        s += v; q += v * v;
    }
    __shared__ float ls[512], lq[512];
    ls[tid] = s; lq[tid] = q;
    __syncthreads();
    if (r == 0) {
        s = ls[d] + ls[d + 128] + ls[d + 256] + ls[d + 384];
        q = lq[d] + lq[d + 128] + lq[d + 256] + lq[d + 384];
        psum[blk * 128 + d] = s;
        psq[blk * 128 + d] = q;
    }
}

__global__ __launch_bounds__(128) void stats_norm(const float* __restrict__ psum,
                                                  const float* __restrict__ psq,
                                                  float* __restrict__ mu_bd,
                                                  float* __restrict__ invn) {
    int d = threadIdx.x;
    float S = 0.f, Q = 0.f;
    float sb[16], qb[16];
    for (int b = 0; b < 16; b++) {
        float s = 0.f, q = 0.f;
        for (int st = 0; st < 16; st++) {
            s += psum[(b * 16 + st) * 128 + d];
            q += psq[(b * 16 + st) * 128 + d];
        }
        sb[b] = s; qb[b] = q; S += s; Q += q;
    }
    float n = (float)(B_ * T_);
    float m = S / n;
    float varu = (Q - n * m * m) / (n - 1.f);
    float sd = sqrtf(fmaxf(varu, 0.f)) + EPS_;
    for (int b = 0; b < 16; b++) {
        float mu = sb[b] * (1.f / T_);
        float varT = qb[b] * (1.f / T_) - mu * mu;
        mu_bd[b * 128 + d] = mu;
        invn[b * 128 + d] = rsqrtf(fmaxf(varT, 0.f) + EPS_ * sd * sd);
    }
}

// ---------------- scan + riders ----------------
// 160 WGs x 512 thr:
//   wg[0..63]    rec(l,b): 8-rows-x-16k tiling, ring[l] -> h_glob[l], flag_h[l]
//   wg[64..127]  xproj(l=0..3,b): l==0 reads norm(x), l>0 reads h[l-1]; fills ring[l]
//   wg[128..143] px rider (R13 shape)
//   wg[144..159] h3-stats rider (R13 shape)
__global__ __attribute__((amdgpu_waves_per_eu(2, 2))) __launch_bounds__(512)
void scan_pipe7(const float* __restrict__ x,
                const float* __restrict__ Wih, const float* __restrict__ Whh,
                const float* __restrict__ bih, const float* __restrict__ bhh,
                const float* __restrict__ proj_x_w, const float* __restrict__ proj_x_b,
                const float* __restrict__ mu_bd, const float* __restrict__ invn,
                float* __restrict__ h_glob,        // [L][B][T][H]
                float* __restrict__ ring,          // [4][B][4][C_][G]
                float* __restrict__ px,            // [B][T][H]
                float* __restrict__ mu_px, float* __restrict__ inv_px,
                float* __restrict__ mu_ln, float* __restrict__ inv_ln,
                int* __restrict__ flag_h,          // [4][B]
                int* __restrict__ flag_g) {        // [4][B]
    const int wg = blockIdx.x;
    const int tid = threadIdx.x;
    __shared__ __align__(16) float shbuf[16 * HROWP_];   // 10240 B, shared by roles

    if (wg < 64) {
        // ======== recurrent consumer (l, b): thread owns 8 rows x k-slice s ========
        const int s = tid & 7, g = tid >> 3;       // k-slice, row-group 0..63
        const int l = wg >> 4, b = wg & 15;
        f4v w[8][4];
        int Rj[8];
        const float* wl = Whh + (size_t)l * G_ * 128;
#pragma unroll
        for (int j = 0; j < 8; j++) {
            Rj[j] = ((j >> 1) << 7) + ((j & 1) << 6) + g;   // gate*128 + (j&1)*64 + g
            LOAD_W4(w[j], wl + (size_t)Rj[j] * 128 + s * 16);
        }
        float c0 = 0.f, c1 = 0.f;
        if (tid < HROWP_) shbuf[tid] = 0.f;        // h buffer 0 (incl. pads)
        const float* rsl = ring + ((size_t)l * 16 + b) * (4 * C_ * G_);
        float* hob = h_glob + ((size_t)l * 16 + b) * T_ * 128;
        int* fg = flag_g + l * 16 + b;
        int* fh = flag_h + l * 16 + b;
        __syncthreads();

        for (int k = 0; k < NCHUNK_; k++) {
            if (tid == 0) wait_ge_(fg, k + 1);
            __syncthreads();
#pragma unroll
            for (int q4 = 0; q4 < 4; q4++) {
                float p[8][4];
                float hr0[4], hr1[4];
                if (s == 0) {
#pragma unroll
                    for (int i = 0; i < 4; i++) {
                        const float* gp = rsl + ((size_t)(k & 3) * C_ + q4 * 4 + i) * G_;
#pragma unroll
                        for (int j = 0; j < 8; j++)
                            p[j][i] = __hip_atomic_load(gp + Rj[j], __ATOMIC_RELAXED, __HIP_MEMORY_SCOPE_AGENT);
                    }
                }
#pragma unroll
                for (int i4 = 0; i4 < 4; i4++) {
                    int t = k * C_ + q4 * 4 + i4;
                    const f4v* hb4 = (const f4v*)(shbuf + (t & 1) * HROWP_ + s * 20);
                    f4v hv[4];
#pragma unroll
                    for (int u = 0; u < 4; u++) hv[u] = hb4[u];
                    float z[8];
#pragma unroll
                    for (int j = 0; j < 8; j++) {
                        DOT16R(z[j], w[j], hv);
                        if (s == 0) z[j] += p[j][i4];
                        z[j] += __shfl_xor(z[j], 1);
                        z[j] += __shfl_xor(z[j], 2);
                        z[j] += __shfl_xor(z[j], 4);
                    }
                    float ai0 = sigmoid_(z[0]), ai1 = sigmoid_(z[1]);
                    float af0 = sigmoid_(z[2]), af1 = sigmoid_(z[3]);
                    float ag0 = tanh_(z[4]),    ag1 = tanh_(z[5]);
                    float ao0 = sigmoid_(z[6]), ao1 = sigmoid_(z[7]);
                    c0 = fmaf(af0, c0, ai0 * ag0);
                    c1 = fmaf(af1, c1, ai1 * ag1);
                    float h0 = ao0 * tanh_(c0);
                    float h1 = ao1 * tanh_(c1);
                    if (s == 0) {
                        shbuf[((t + 1) & 1) * HROWP_ + HOFFP(g)] = h0;
                        shbuf[((t + 1) & 1) * HROWP_ + HOFFP(g + 64)] = h1;
                        hr0[i4] = h0; hr1[i4] = h1;
                    }
                    __syncthreads();
                }
                if (s == 0) {
#pragma unroll
                    for (int i = 0; i < 4; i++) {
                        int t = k * C_ + q4 * 4 + i;
                        __hip_atomic_store(hob + (size_t)t * 128 + g, hr0[i],
                                           __ATOMIC_RELAXED, __HIP_MEMORY_SCOPE_AGENT);
                        __hip_atomic_store(hob + (size_t)t * 128 + 64 + g, hr1[i],
                                           __ATOMIC_RELAXED, __HIP_MEMORY_SCOPE_AGENT);
                    }
                }
            }
            __syncthreads();   // drains vmcnt: all chunk h-stores visible
            if (tid == 0) __hip_atomic_store(fh, k + 1, __ATOMIC_RELEASE, __HIP_MEMORY_SCOPE_AGENT);
        }
    } else if (wg < 128) {
        // ======== xproj producer (layers 0..3), same 8x16 tiling ========
        const int s = tid & 7, g = tid >> 3;
        const int l = (wg - 64) >> 4, b = (wg - 64) & 15;
        f4v w[8][4];
        int Rj[8];
        float bs[8];
        const float* wl = Wih + (size_t)l * G_ * 128;
#pragma unroll
        for (int j = 0; j < 8; j++) {
            Rj[j] = ((j >> 1) << 7) + ((j & 1) << 6) + g;
            LOAD_W4(w[j], wl + (size_t)Rj[j] * 128 + s * 16);
            bs[j] = bih[l * G_ + Rj[j]] + bhh[l * G_ + Rj[j]];
        }
        const float* hsrc = (l > 0) ? h_glob + ((size_t)(l - 1) * 16 + b) * T_ * 128
                                    : x + (size_t)b * T_ * 128;
        float muk = 0.f, ivk = 1.f;
        if (l == 0) { muk = mu_bd[b * 128 + (tid & 127)]; ivk = invn[b * 128 + (tid & 127)]; }
        float* rout = ring + ((size_t)l * 16 + b) * (4 * C_ * G_);
        int* fhp = (l > 0) ? flag_h + (l - 1) * 16 + b : flag_h;
        int* fhme = flag_h + l * 16 + b;
        int* fgo = flag_g + l * 16 + b;

        for (int k = 0; k < NCHUNK_; k++) {
            if (tid == 0) {
                if (l > 0) wait_ge_(fhp, k + 1);
                if (k >= 4) wait_ge_(fhme, k - 3);
            }
            __syncthreads();
#pragma unroll
            for (int i = 0; i < 4; i++) {
                int idx = i * 512 + tid;
                int step = idx >> 7, kk = idx & 127;
                float v;
                if (l == 0) {
                    v = hsrc[(size_t)k * C_ * 128 + idx];
                    v = (v - muk) * ivk;
                } else {
                    v = __hip_atomic_load(hsrc + (size_t)k * C_ * 128 + idx,
                                          __ATOMIC_RELAXED, __HIP_MEMORY_SCOPE_AGENT);
                }
                shbuf[step * HROWP_ + HOFFP(kk)] = v;
            }
            __syncthreads();
#pragma unroll
            for (int st = 0; st < C_; st++) {
                const f4v* hb4 = (const f4v*)(shbuf + st * HROWP_ + s * 20);
                f4v hv[4];
#pragma unroll
                for (int u = 0; u < 4; u++) hv[u] = hb4[u];
                float z[8];
#pragma unroll
                for (int j = 0; j < 8; j++) {
                    DOT16R(z[j], w[j], hv);
                    z[j] += __shfl_xor(z[j], 1);
                    z[j] += __shfl_xor(z[j], 2);
                    z[j] += __shfl_xor(z[j], 4);
                }
                if (s == 0) {
                    float* ro = rout + ((size_t)(k & 3) * C_ + st) * G_;
#pragma unroll
                    for (int j = 0; j < 8; j++)
                        __hip_atomic_store(ro + Rj[j], z[j] + bs[j],
                                           __ATOMIC_RELAXED, __HIP_MEMORY_SCOPE_AGENT);
                }
            }
            __syncthreads();   // drains vmcnt: ring chunk visible
            if (tid == 0) __hip_atomic_store(fgo, k + 1, __ATOMIC_RELEASE, __HIP_MEMORY_SCOPE_AGENT);
        }
    } else if (wg < 144) {
        // ======== px rider (unchanged R13 shape) ========
        const int b = wg - 128;
        const int h = tid & 127, tq = tid >> 7;
        f4v w0[8], w1[8], w2[8], w3[8];
        LOAD_W8(w0, proj_x_w + (size_t)h * 128 + 0);
        LOAD_W8(w1, proj_x_w + (size_t)h * 128 + 32);
        LOAD_W8(w2, proj_x_w + (size_t)h * 128 + 64);
        LOAD_W8(w3, proj_x_w + (size_t)h * 128 + 96);
        float bsx = proj_x_b[h];
        float muk = mu_bd[b * 128 + h], ivk = invn[b * 128 + h];
        const float* xb = x + (size_t)b * T_ * 128;
        float* pxb = px + (size_t)b * T_ * 128;
        float sacc = 0.f, qacc = 0.f;

        for (int blk = 0; blk < 16; blk++) {
            int t0 = blk * 16;
            __syncthreads();
#pragma unroll
            for (int j = 0; j < 4; j++) {
                int tt = tq * 4 + j;
                float v = xb[(size_t)(t0 + tt) * 128 + h];
                shbuf[tt * HROW_ + HOFF(h)] = (v - muk) * ivk;
            }
            __syncthreads();
#pragma unroll
            for (int j = 0; j < 4; j++) {
                int tt = tq * 4 + j;
                const float* row = shbuf + tt * HROW_;
                f4v hv[8];
                float p0, p1, p2, p3;
                const f4v* r4 = (const f4v*)(row + 0 * 36);
#pragma unroll
                for (int u = 0; u < 8; u++) hv[u] = r4[u];
                DOT32R(p0, w0, hv);
                r4 = (const f4v*)(row + 1 * 36);
#pragma unroll
                for (int u = 0; u < 8; u++) hv[u] = r4[u];
                DOT32R(p1, w1, hv);
                r4 = (const f4v*)(row + 2 * 36);
#pragma unroll
                for (int u = 0; u < 8; u++) hv[u] = r4[u];
                DOT32R(p2, w2, hv);
                r4 = (const f4v*)(row + 3 * 36);
#pragma unroll
                for (int u = 0; u < 8; u++) hv[u] = r4[u];
                DOT32R(p3, w3, hv);
                float val = (p0 + p1) + (p2 + p3) + bsx;
                pxb[(size_t)(t0 + tt) * 128 + h] = val;
                sacc += val; qacc += val * val;
            }
        }
        __syncthreads();
        shbuf[tq * 128 + h] = sacc;
        shbuf[512 + tq * 128 + h] = qacc;
        __syncthreads();
        if (tq == 0) {
            float s = shbuf[h] + shbuf[128 + h] + shbuf[256 + h] + shbuf[384 + h];
            float qq = shbuf[512 + h] + shbuf[640 + h] + shbuf[768 + h] + shbuf[896 + h];
            float m = s * (1.f / T_);
            float v = qq * (1.f / T_) - m * m;
            mu_px[b * 128 + h] = m;
            inv_px[b * 128 + h] = rsqrtf(fmaxf(v, 0.f) + EPS_);
        }
    } else {
        // ======== h3-stats rider (unchanged R13 shape) ========
        const int b = wg - 144;
        const int h = tid & 127, st = tid >> 7;
        const float* hsrc = h_glob + ((size_t)3 * 16 + b) * T_ * 128;
        int* f3 = flag_h + 3 * 16 + b;
        float s = 0.f, q = 0.f;
        for (int k = 0; k < NCHUNK_; k++) {
            if (tid == 0) wait_ge_(f3, k + 1);
            __syncthreads();
#pragma unroll
            for (int j = 0; j < 4; j++) {
                int tt = st * 4 + j;
                float v = __hip_atomic_load(hsrc + (size_t)(k * C_ + tt) * 128 + h,
                                            __ATOMIC_RELAXED, __HIP_MEMORY_SCOPE_AGENT);
                s += v; q += v * v;
            }
        }
        shbuf[st * 128 + h] = s;
        shbuf[512 + st * 128 + h] = q;
        __syncthreads();
        if (st == 0) {
            float ss = shbuf[h] + shbuf[128 + h] + shbuf[256 + h] + shbuf[384 + h];
            float qq = shbuf[512 + h] + shbuf[640 + h] + shbuf[768 + h] + shbuf[896 + h];
            float m = ss * (1.f / T_);
            float v = qq * (1.f / T_) - m * m;
            mu_ln[b * 128 + h] = m;
            inv_ln[b * 128 + h] = rsqrtf(fmaxf(v, 0.f) + EPS_);
        }
    }
}

// ---------------- ph GEMM (IN fused on load) + per-row attention score ----------
__global__ __launch_bounds__(256) void gemm_score(const float* __restrict__ A,   // h3
                                                  const float* __restrict__ mu,
                                                  const float* __restrict__ inv,
                                                  const float* __restrict__ Bw,
                                                  const float* __restrict__ b1,
                                                  const float* __restrict__ px,
                                                  const float* __restrict__ mu_px,
                                                  const float* __restrict__ inv_px,
                                                  const float* __restrict__ attn_w,
                                                  float* __restrict__ ph,
                                                  float* __restrict__ lsc) {
    __shared__ __align__(16) float As[16][64];
    __shared__ __align__(16) float Bs[16][128];
    __shared__ float red[64][17];
    int tid = threadIdx.x;
    int m0 = blockIdx.x * 64;
    int lr = tid >> 2, lc = (tid & 3) << 2;
    int lrB = tid >> 1, lcB = (tid & 1) << 3;
    int tr = tid >> 4, tc = tid & 15;
    int tm = tr << 2, tn = tc << 3;
    float acc[4][8] = {};
    int bidx = (m0 + lr) >> 8;
    const float* Arow = A + (size_t)(m0 + lr) * 128 + lc;
    const float* mup = mu + bidx * 128 + lc;
    const float* ivp = inv + bidx * 128 + lc;
    const float* Brow = Bw + (size_t)lrB * 128 + lcB;
    for (int kb = 0; kb < 128; kb += 16) {
        float4 av = *(const float4*)(Arow + kb);
        float4 m4 = *(const float4*)(mup + kb);
        float4 i4 = *(const float4*)(ivp + kb);
        av.x = (av.x - m4.x) * i4.x; av.y = (av.y - m4.y) * i4.y;
        av.z = (av.z - m4.z) * i4.z; av.w = (av.w - m4.w) * i4.w;
        float4 bv0 = *(const float4*)(Brow + kb);
        float4 bv1 = *(const float4*)(Brow + kb + 4);
        __syncthreads();
        As[lc + 0][lr] = av.x; As[lc + 1][lr] = av.y; As[lc + 2][lr] = av.z; As[lc + 3][lr] = av.w;
        Bs[lcB + 0][lrB] = bv0.x; Bs[lcB + 1][lrB] = bv0.y; Bs[lcB + 2][lrB] = bv0.z; Bs[lcB + 3][lrB] = bv0.w;
        Bs[lcB + 4][lrB] = bv1.x; Bs[lcB + 5][lrB] = bv1.y; Bs[lcB + 6][lrB] = bv1.z; Bs[lcB + 7][lrB] = bv1.w;
        __syncthreads();
#pragma unroll
        for (int k = 0; k < 16; k++) {
            float ar[4], br[8];
#pragma unroll
            for (int i = 0; i < 4; i++) ar[i] = As[k][tm + i];
#pragma unroll
            for (int j = 0; j < 8; j++) br[j] = Bs[k][tn + j];
#pragma unroll
            for (int i = 0; i < 4; i++)
#pragma unroll
                for (int j = 0; j < 8; j++)
                    acc[i][j] = fmaf(ar[i], br[j], acc[i][j]);
        }
    }
    float spart[4];
#pragma unroll
    for (int i = 0; i < 4; i++) {
        int row = m0 + tm + i;
        int bb = row >> 8;
        float sp = 0.f;
#pragma unroll
        for (int j = 0; j < 8; j++) {
            int col = tn + j;
            float val = acc[i][j] + b1[col];
            ph[(size_t)row * 128 + col] = val;
            float inx = (px[(size_t)row * 128 + col] - mu_px[bb * 128 + col]) * inv_px[bb * 128 + col];
            sp = fmaf(tanh_(val + inx), attn_w[col], sp);
        }
        spart[i] = sp;
    }
    __syncthreads();
#pragma unroll
    for (int i = 0; i < 4; i++) red[tm + i][tc] = spart[i];
    __syncthreads();
    if (tid < 64) {
        float s = 0.f;
#pragma unroll
        for (int j = 0; j < 16; j++) s += red[tid][j];
        lsc[m0 + tid] = s;
    }
}

// ---------------- tail4: softmax + att map quarter + classify (64 WGs) -------------
__global__ __launch_bounds__(256) void tail4(const float* __restrict__ lsc,
                                             const float* __restrict__ ph,
                                             const float* __restrict__ fc_w,
                                             const float* __restrict__ fc_b,
                                             float* __restrict__ out,
                                             float* __restrict__ out_att) {
    int b = blockIdx.x >> 2, qt = blockIdx.x & 3;
    int tid = threadIdx.x;
    int h = tid & 127, st = tid >> 7;
    const float* phb = ph + (size_t)b * T_ * H_;
    __shared__ float tmp[256], wsh[256], ls[256];
    float v = lsc[b * 256 + tid];
    tmp[tid] = v; __syncthreads();
    for (int off = 128; off > 0; off >>= 1) { if (tid < off) tmp[tid] = fmaxf(tmp[tid], tmp[tid + off]); __syncthreads(); }
    float mx = tmp[0]; __syncthreads();
    float e = __expf(v - mx);
    tmp[tid] = e; __syncthreads();
    for (int off = 128; off > 0; off >>= 1) { if (tid < off) tmp[tid] += tmp[tid + off]; __syncthreads(); }
    wsh[tid] = e / tmp[0];
    __syncthreads();
    {   // attention-map quarter: t rows [qt*64, qt*64+64)
        float* ob = out_att + (size_t)b * T_ * D_;
        const float invD = 1.f / (float)D_;
        int base = qt * 64 * 128;
        for (int i = tid; i < 64 * 128; i += 256) ob[base + i] = wsh[(base + i) >> 7] * invD;
    }
    if (qt == 0) {   // context + FC
        float acc = 0.f;
        for (int t = st; t < T_; t += 2) acc = fmaf(phb[t * 128 + h], wsh[t], acc);
        ls[tid] = acc;
        __syncthreads();
        if (tid < 128) ls[tid] = ls[tid] + ls[tid + 128];
        __syncthreads();
        if (tid < NC_) {
            float s = fc_b[tid];
            const float* fw = fc_w + tid * 128;
            for (int k = 0; k < 128; k++) s = fmaf(ls[k], fw[k], s);
            out[b * NC_ + tid] = s;
        }
    }
}

// ---------------- launcher ----------------
extern "C" void kernel_launch(void* const* d_in, const int* in_sizes, int n_in,
                              void* d_out, int out_size, void* d_ws, size_t ws_size,
                              hipStream_t stream) {
    const float* x        = (const float*)d_in[0];
    const float* Wih      = (const float*)d_in[1];
    const float* Whh      = (const float*)d_in[2];
    const float* bih      = (const float*)d_in[3];
    const float* bhh      = (const float*)d_in[4];
    const float* proj_h_w = (const float*)d_in[5];
    const float* proj_h_b = (const float*)d_in[6];
    const float* proj_x_w = (const float*)d_in[7];
    const float* proj_x_b = (const float*)d_in[8];
    const float* attn_w   = (const float*)d_in[9];
    const float* fc_w     = (const float*)d_in[10];
    const float* fc_b     = (const float*)d_in[11];
    float* out = (float*)d_out;

    float* ws = (float*)d_ws;
    const size_t NTD = (size_t)B_ * T_ * D_;       // 524288
    float* h_glob = ws;                            // 4*NTD
    float* ring   = h_glob + 4 * NTD;              // 4*NTD
    float* px     = ring + 4 * NTD;                // 1*NTD
    float* smalls = px + NTD;
    float* psum   = smalls;                        // 256*128
    float* psq    = psum + 32768;                  // 256*128
    float* mu_bd  = psq + 32768;
    float* invn   = mu_bd + 2048;
    float* mu_ln  = invn + 2048;
    float* inv_ln = mu_ln + 2048;
    float* mu_px  = inv_ln + 2048;
    float* inv_px = mu_px + 2048;
    float* lsc    = inv_px + 2048;
    int*   flags  = (int*)(lsc + 4096);
    int*   flag_h = flags;                         // [64]
    int*   flag_g = flags + 64;                    // [64]
    float* ph = h_glob;                            // post-scan reuse
    const float* h3 = h_glob + 3 * NTD;

    hipMemsetAsync((void*)flags, 0, 128 * sizeof(int), stream);

    // head: parallel partial stats + fused-normalization factors (tiny)
    stats_bd<<<256, 512, 0, stream>>>(x, psum, psq);
    stats_norm<<<1, 128, 0, stream>>>(psum, psq, mu_bd, invn);

    // the whole pipeline-shaped middle: 4-layer LSTM + all riders
    scan_pipe7<<<160, 512, 0, stream>>>(x, Wih, Whh, bih, bhh,
                                        proj_x_w, proj_x_b, mu_bd, invn,
                                        h_glob, ring, px, mu_px, inv_px,
                                        mu_ln, inv_ln, flag_h, flag_g);

    // ph = IN(h3) @ proj_h_w^T + b, fused with attention scores
    gemm_score<<<64, 256, 0, stream>>>(h3, mu_ln, inv_ln, proj_h_w, proj_h_b,
                                       px, mu_px, inv_px, attn_w, ph, lsc);

    // softmax + attention map + classify (4 WGs per batch)
    tail4<<<64, 256, 0, stream>>>(lsc, ph, fc_w, fc_b, out, out + B_ * NC_);
}

// Round 15
// 486.172 us; speedup vs baseline: 1.5421x; 1.5421x over previous
//
#include <hip/hip_runtime.h>
#include <math.h>
#include <cstddef>

#define B_ 16
#define T_ 256
#define D_ 128
#define H_ 128
#define L_ 4
#define G_ 512          // 4*H
#define NC_ 10
#define EPS_ 1e-5f
#define C_ 16           // pipeline chunk (timesteps per flag)
#define NCHUNK_ (T_ / C_)

// padded LDS row: +4 floats per 32 -> 144-float rows; quarter q at q*36 floats
#define HROW_ 144
#define HOFF(k) ((k) + (((k) >> 5) << 2))

typedef float f4v __attribute__((ext_vector_type(4)));

// 8 x global_load_dwordx4 -> 32 floats resident (compiler cannot remat asm)
#define LOAD_W8(w, base)                                                   \
    asm volatile(                                                          \
        "global_load_dwordx4 %0, %8, off\n\t"                             \
        "global_load_dwordx4 %1, %8, off offset:16\n\t"                   \
        "global_load_dwordx4 %2, %8, off offset:32\n\t"                   \
        "global_load_dwordx4 %3, %8, off offset:48\n\t"                   \
        "global_load_dwordx4 %4, %8, off offset:64\n\t"                   \
        "global_load_dwordx4 %5, %8, off offset:80\n\t"                   \
        "global_load_dwordx4 %6, %8, off offset:96\n\t"                   \
        "global_load_dwordx4 %7, %8, off offset:112\n\t"                  \
        "s_waitcnt vmcnt(0)"                                               \
        : "=&v"(w[0]), "=&v"(w[1]), "=&v"(w[2]), "=&v"(w[3]),              \
          "=&v"(w[4]), "=&v"(w[5]), "=&v"(w[6]), "=&v"(w[7])               \
        : "v"(base)                                                        \
        : "memory")

// 32-k partial dot against pre-loaded h registers (params avoid x/y/z/w tokens)
#define DOT32R(dst_, warr_, hvarr_)                                        \
    {                                                                      \
        float d0_ = 0.f, d1_ = 0.f;                                        \
        _Pragma("unroll")                                                  \
        for (int j_ = 0; j_ < 8; j_++) {                                   \
            d0_ = fmaf(warr_[j_].x, hvarr_[j_].x, d0_);                    \
            d1_ = fmaf(warr_[j_].y, hvarr_[j_].y, d1_);                    \
            d0_ = fmaf(warr_[j_].z, hvarr_[j_].z, d0_);                    \
            d1_ = fmaf(warr_[j_].w, hvarr_[j_].w, d1_);                    \
        }                                                                  \
        dst_ = d0_ + d1_;                                                  \
    }

// ---------------- device helpers ----------------
__device__ __forceinline__ float sigmoid_(float x) {
    x = fminf(fmaxf(x, -30.f), 30.f);
    return 1.f / (1.f + __expf(-x));
}
__device__ __forceinline__ float tanh_(float x) {
    float ax = fminf(fabsf(x), 15.f);
    float e = __expf(2.f * ax);
    float t = 1.f - 2.f / (e + 1.f);
    return copysignf(t, x);
}
__device__ __forceinline__ void wait_ge_(int* p, int v) {
    if (__hip_atomic_load(p, __ATOMIC_RELAXED, __HIP_MEMORY_SCOPE_AGENT) < v) {
        do { __builtin_amdgcn_s_sleep(1); }
        while (__hip_atomic_load(p, __ATOMIC_RELAXED, __HIP_MEMORY_SCOPE_AGENT) < v);
    }
    (void)__hip_atomic_load(p, __ATOMIC_ACQUIRE, __HIP_MEMORY_SCOPE_AGENT);
}

// ---------------- head: per-(b,strip) partial stats (256 WGs) ----------------
__global__ __launch_bounds__(512) void stats_bd(const float* __restrict__ x,
                                                float* __restrict__ psum,
                                                float* __restrict__ psq) {
    int blk = blockIdx.x;                 // b*16 + strip
    int b = blk >> 4, strip = blk & 15;
    int tid = threadIdx.x;
    int d = tid & 127, r = tid >> 7;
    const float* xb = x + (size_t)b * T_ * D_ + (size_t)strip * 16 * D_;
    float s = 0.f, q = 0.f;
    for (int t = r; t < 16; t += 4) {
        float v = xb[t * D_ + d];
        s += v; q += v * v;
    }
    __shared__ float ls[512], lq[512];
    ls[tid] = s; lq[tid] = q;
    __syncthreads();
    if (r == 0) {
        s = ls[d] + ls[d + 128] + ls[d + 256] + ls[d + 384];
        q = lq[d] + lq[d + 128] + lq[d + 256] + lq[d + 384];
        psum[blk * 128 + d] = s;
        psq[blk * 128 + d] = q;
    }
}

__global__ __launch_bounds__(128) void stats_norm(const float* __restrict__ psum,
                                                  const float* __restrict__ psq,
                                                  float* __restrict__ mu_bd,
                                                  float* __restrict__ invn) {
    int d = threadIdx.x;
    float S = 0.f, Q = 0.f;
    float sb[16], qb[16];
    for (int b = 0; b < 16; b++) {
        float s = 0.f, q = 0.f;
        for (int st = 0; st < 16; st++) {
            s += psum[(b * 16 + st) * 128 + d];
            q += psq[(b * 16 + st) * 128 + d];
        }
        sb[b] = s; qb[b] = q; S += s; Q += q;
    }
    float n = (float)(B_ * T_);
    float m = S / n;
    float varu = (Q - n * m * m) / (n - 1.f);
    float sd = sqrtf(fmaxf(varu, 0.f)) + EPS_;
    for (int b = 0; b < 16; b++) {
        float mu = sb[b] * (1.f / T_);
        float varT = qb[b] * (1.f / T_) - mu * mu;
        mu_bd[b * 128 + d] = mu;
        invn[b * 128 + d] = rsqrtf(fmaxf(varT, 0.f) + EPS_ * sd * sd);
    }
}

// ---------------- scan + riders (R13-proven structure) ----------------
// 160 WGs x 512 thr:
//   wg[0..63]    rec(l,b): quad row-sharing (R10/R13 tiling — proven optimum)
//   wg[64..127]  xproj(l=0..3,b): l==0 reads norm(x) (no wait); fills ring[l]
//   wg[128..143] px rider
//   wg[144..159] h3-stats rider
__global__ __attribute__((amdgpu_waves_per_eu(2, 2))) __launch_bounds__(512)
void scan_pipe6(const float* __restrict__ x,
                const float* __restrict__ Wih, const float* __restrict__ Whh,
                const float* __restrict__ bih, const float* __restrict__ bhh,
                const float* __restrict__ proj_x_w, const float* __restrict__ proj_x_b,
                const float* __restrict__ mu_bd, const float* __restrict__ invn,
                float* __restrict__ h_glob,        // [L][B][T][H]
                float* __restrict__ ring,          // [4][B][4][C_][G]
                float* __restrict__ px,            // [B][T][H]
                float* __restrict__ mu_px, float* __restrict__ inv_px,
                float* __restrict__ mu_ln, float* __restrict__ inv_ln,
                int* __restrict__ flag_h,          // [4][B]
                int* __restrict__ flag_g) {        // [4][B]
    const int wg = blockIdx.x;
    const int tid = threadIdx.x;
    __shared__ __align__(16) float shbuf[16 * HROW_];   // 9216 B, shared by all roles

    if (wg < 64) {
        // ======== recurrent consumer (l, b) ========
        const int r = tid >> 2, q = tid & 3;
        const int l = wg >> 4, b = wg & 15;
        f4v w0[8], w1[8], w2[8], w3[8];
        const float* wl = Whh + (size_t)l * G_ * 128;
        LOAD_W8(w0, wl + ((size_t)(0 * 128 + r)) * 128 + q * 32);
        LOAD_W8(w1, wl + ((size_t)(1 * 128 + r)) * 128 + q * 32);
        LOAD_W8(w2, wl + ((size_t)(2 * 128 + r)) * 128 + q * 32);
        LOAD_W8(w3, wl + ((size_t)(3 * 128 + r)) * 128 + q * 32);
        float c = 0.f;
        if (tid < HROW_) shbuf[tid] = 0.f;               // h buffer 0
        const float* rsl = ring + ((size_t)l * 16 + b) * (4 * C_ * G_);
        float* hob = h_glob + ((size_t)l * 16 + b) * T_ * 128;
        int* fg = flag_g + l * 16 + b;
        int* fh = flag_h + l * 16 + b;
        float hreg[C_];
        __syncthreads();

        for (int k = 0; k < NCHUNK_; k++) {
            if (tid == 0) wait_ge_(fg, k + 1);
            __syncthreads();
#pragma unroll
            for (int half = 0; half < 2; half++) {
                float p0[8], p1[8], p2[8], p3[8];
#pragma unroll
                for (int s8 = 0; s8 < 8; s8++) {
                    int s = half * 8 + s8;
                    const float* gp = rsl + ((size_t)(k & 3) * C_ + s) * G_;
                    p0[s8] = __hip_atomic_load(gp + r, __ATOMIC_RELAXED, __HIP_MEMORY_SCOPE_AGENT);
                    p1[s8] = __hip_atomic_load(gp + 128 + r, __ATOMIC_RELAXED, __HIP_MEMORY_SCOPE_AGENT);
                    p2[s8] = __hip_atomic_load(gp + 256 + r, __ATOMIC_RELAXED, __HIP_MEMORY_SCOPE_AGENT);
                    p3[s8] = __hip_atomic_load(gp + 384 + r, __ATOMIC_RELAXED, __HIP_MEMORY_SCOPE_AGENT);
                }
#pragma unroll
                for (int s8 = 0; s8 < 8; s8++) {
                    int s = half * 8 + s8;
                    int t = k * C_ + s;
                    const f4v* hb4 = (const f4v*)(shbuf + (t & 1) * HROW_ + q * 36);
                    f4v hv[8];
#pragma unroll
                    for (int j = 0; j < 8; j++) hv[j] = hb4[j];
                    float zi, zf, zg, zo;
                    DOT32R(zi, w0, hv);
                    DOT32R(zf, w1, hv);
                    DOT32R(zg, w2, hv);
                    DOT32R(zo, w3, hv);
                    zi += __shfl_xor(zi, 1); zi += __shfl_xor(zi, 2);
                    zf += __shfl_xor(zf, 1); zf += __shfl_xor(zf, 2);
                    zg += __shfl_xor(zg, 1); zg += __shfl_xor(zg, 2);
                    zo += __shfl_xor(zo, 1); zo += __shfl_xor(zo, 2);
                    zi += p0[s8]; zf += p1[s8]; zg += p2[s8]; zo += p3[s8];
                    float ai = sigmoid_(zi), af = sigmoid_(zf);
                    float ag = tanh_(zg),    ao = sigmoid_(zo);
                    c = fmaf(af, c, ai * ag);
                    float hn = ao * tanh_(c);
                    if (q == 0) shbuf[((t + 1) & 1) * HROW_ + HOFF(r)] = hn;
                    hreg[s] = hn;
                    __syncthreads();
                }
            }
            if (q == 0) {
#pragma unroll
                for (int s = 0; s < C_; s++)
                    __hip_atomic_store(hob + (size_t)(k * C_ + s) * 128 + r, hreg[s],
                                       __ATOMIC_RELAXED, __HIP_MEMORY_SCOPE_AGENT);
            }
            __syncthreads();
            if (tid == 0) __hip_atomic_store(fh, k + 1, __ATOMIC_RELEASE, __HIP_MEMORY_SCOPE_AGENT);
        }
    } else if (wg < 128) {
        // ======== xproj producer (layers 0..3) ========
        const int r = tid >> 2, q = tid & 3;
        const int l = (wg - 64) >> 4, b = (wg - 64) & 15;
        f4v w0[8], w1[8], w2[8], w3[8];
        const float* wl = Wih + (size_t)l * G_ * 128;
        LOAD_W8(w0, wl + ((size_t)(0 * 128 + r)) * 128 + q * 32);
        LOAD_W8(w1, wl + ((size_t)(1 * 128 + r)) * 128 + q * 32);
        LOAD_W8(w2, wl + ((size_t)(2 * 128 + r)) * 128 + q * 32);
        LOAD_W8(w3, wl + ((size_t)(3 * 128 + r)) * 128 + q * 32);
        float bs0 = bih[l * G_ + r] + bhh[l * G_ + r];
        float bs1 = bih[l * G_ + 128 + r] + bhh[l * G_ + 128 + r];
        float bs2 = bih[l * G_ + 256 + r] + bhh[l * G_ + 256 + r];
        float bs3 = bih[l * G_ + 384 + r] + bhh[l * G_ + 384 + r];
        const float* hsrc = (l > 0) ? h_glob + ((size_t)(l - 1) * 16 + b) * T_ * 128
                                    : x + (size_t)b * T_ * 128;
        float muk = 0.f, ivk = 1.f;
        if (l == 0) { muk = mu_bd[b * 128 + (tid & 127)]; ivk = invn[b * 128 + (tid & 127)]; }
        float* rout = ring + ((size_t)l * 16 + b) * (4 * C_ * G_);
        int* fhp = (l > 0) ? flag_h + (l - 1) * 16 + b : flag_h;
        int* fhme = flag_h + l * 16 + b;
        int* fgo = flag_g + l * 16 + b;

        for (int k = 0; k < NCHUNK_; k++) {
            if (tid == 0) {
                if (l > 0) wait_ge_(fhp, k + 1);
                if (k >= 4) wait_ge_(fhme, k - 3);
            }
            __syncthreads();
#pragma unroll
            for (int i = 0; i < 4; i++) {
                int idx = i * 512 + tid;
                float v;
                if (l == 0) {
                    v = hsrc[(size_t)k * C_ * 128 + idx];
                    v = (v - muk) * ivk;
                } else {
                    v = __hip_atomic_load(hsrc + (size_t)k * C_ * 128 + idx,
                                          __ATOMIC_RELAXED, __HIP_MEMORY_SCOPE_AGENT);
                }
                shbuf[(idx >> 7) * HROW_ + HOFF(idx & 127)] = v;
            }
            __syncthreads();
#pragma unroll
            for (int s = 0; s < C_; s++) {
                const f4v* hb4 = (const f4v*)(shbuf + s * HROW_ + q * 36);
                f4v hv[8];
#pragma unroll
                for (int j = 0; j < 8; j++) hv[j] = hb4[j];
                float z0, z1, z2, z3;
                DOT32R(z0, w0, hv);
                DOT32R(z1, w1, hv);
                DOT32R(z2, w2, hv);
                DOT32R(z3, w3, hv);
                z0 += __shfl_xor(z0, 1); z0 += __shfl_xor(z0, 2);
                z1 += __shfl_xor(z1, 1); z1 += __shfl_xor(z1, 2);
                z2 += __shfl_xor(z2, 1); z2 += __shfl_xor(z2, 2);
                z3 += __shfl_xor(z3, 1); z3 += __shfl_xor(z3, 2);
                if (q == 0) {
                    float* ro = rout + ((size_t)(k & 3) * C_ + s) * G_;
                    __hip_atomic_store(ro + r, z0 + bs0, __ATOMIC_RELAXED, __HIP_MEMORY_SCOPE_AGENT);
                    __hip_atomic_store(ro + 128 + r, z1 + bs1, __ATOMIC_RELAXED, __HIP_MEMORY_SCOPE_AGENT);
                    __hip_atomic_store(ro + 256 + r, z2 + bs2, __ATOMIC_RELAXED, __HIP_MEMORY_SCOPE_AGENT);
                    __hip_atomic_store(ro + 384 + r, z3 + bs3, __ATOMIC_RELAXED, __HIP_MEMORY_SCOPE_AGENT);
                }
            }
            __syncthreads();
            if (tid == 0) __hip_atomic_store(fgo, k + 1, __ATOMIC_RELEASE, __HIP_MEMORY_SCOPE_AGENT);
        }
    } else if (wg < 144) {
        // ======== px rider: px[b] = norm(x[b]) @ proj_x_w^T + b; + IN stats ========
        const int b = wg - 128;
        const int h = tid & 127, tq = tid >> 7;
        f4v w0[8], w1[8], w2[8], w3[8];
        LOAD_W8(w0, proj_x_w + (size_t)h * 128 + 0);
        LOAD_W8(w1, proj_x_w + (size_t)h * 128 + 32);
        LOAD_W8(w2, proj_x_w + (size_t)h * 128 + 64);
        LOAD_W8(w3, proj_x_w + (size_t)h * 128 + 96);
        float bsx = proj_x_b[h];
        float muk = mu_bd[b * 128 + h], ivk = invn[b * 128 + h];
        const float* xb = x + (size_t)b * T_ * 128;
        float* pxb = px + (size_t)b * T_ * 128;
        float sacc = 0.f, qacc = 0.f;

        for (int blk = 0; blk < 16; blk++) {
            int t0 = blk * 16;
            __syncthreads();
#pragma unroll
            for (int j = 0; j < 4; j++) {
                int tt = tq * 4 + j;
                float v = xb[(size_t)(t0 + tt) * 128 + h];
                shbuf[tt * HROW_ + HOFF(h)] = (v - muk) * ivk;
            }
            __syncthreads();
#pragma unroll
            for (int j = 0; j < 4; j++) {
                int tt = tq * 4 + j;
                const float* row = shbuf + tt * HROW_;
                f4v hv[8];
                float p0, p1, p2, p3;
                const f4v* r4 = (const f4v*)(row + 0 * 36);
#pragma unroll
                for (int u = 0; u < 8; u++) hv[u] = r4[u];
                DOT32R(p0, w0, hv);
                r4 = (const f4v*)(row + 1 * 36);
#pragma unroll
                for (int u = 0; u < 8; u++) hv[u] = r4[u];
                DOT32R(p1, w1, hv);
                r4 = (const f4v*)(row + 2 * 36);
#pragma unroll
                for (int u = 0; u < 8; u++) hv[u] = r4[u];
                DOT32R(p2, w2, hv);
                r4 = (const f4v*)(row + 3 * 36);
#pragma unroll
                for (int u = 0; u < 8; u++) hv[u] = r4[u];
                DOT32R(p3, w3, hv);
                float val = (p0 + p1) + (p2 + p3) + bsx;
                pxb[(size_t)(t0 + tt) * 128 + h] = val;
                sacc += val; qacc += val * val;
            }
        }
        __syncthreads();
        shbuf[tq * 128 + h] = sacc;
        shbuf[512 + tq * 128 + h] = qacc;
        __syncthreads();
        if (tq == 0) {
            float s = shbuf[h] + shbuf[128 + h] + shbuf[256 + h] + shbuf[384 + h];
            float qq = shbuf[512 + h] + shbuf[640 + h] + shbuf[768 + h] + shbuf[896 + h];
            float m = s * (1.f / T_);
            float v = qq * (1.f / T_) - m * m;
            mu_px[b * 128 + h] = m;
            inv_px[b * 128 + h] = rsqrtf(fmaxf(v, 0.f) + EPS_);
        }
    } else {
        // ======== h3-stats rider: IN stats of layer-3 h, chunk-incremental ========
        const int b = wg - 144;
        const int h = tid & 127, st = tid >> 7;
        const float* hsrc = h_glob + ((size_t)3 * 16 + b) * T_ * 128;
        int* f3 = flag_h + 3 * 16 + b;
        float s = 0.f, q = 0.f;
        for (int k = 0; k < NCHUNK_; k++) {
            if (tid == 0) wait_ge_(f3, k + 1);
            __syncthreads();
#pragma unroll
            for (int j = 0; j < 4; j++) {
                int tt = st * 4 + j;
                float v = __hip_atomic_load(hsrc + (size_t)(k * C_ + tt) * 128 + h,
                                            __ATOMIC_RELAXED, __HIP_MEMORY_SCOPE_AGENT);
                s += v; q += v * v;
            }
        }
        shbuf[st * 128 + h] = s;
        shbuf[512 + st * 128 + h] = q;
        __syncthreads();
        if (st == 0) {
            float ss = shbuf[h] + shbuf[128 + h] + shbuf[256 + h] + shbuf[384 + h];
            float qq = shbuf[512 + h] + shbuf[640 + h] + shbuf[768 + h] + shbuf[896 + h];
            float m = ss * (1.f / T_);
            float v = qq * (1.f / T_) - m * m;
            mu_ln[b * 128 + h] = m;
            inv_ln[b * 128 + h] = rsqrtf(fmaxf(v, 0.f) + EPS_);
        }
    }
}

// ---------------- ph GEMM (IN fused on load) + per-row attention score ----------
__global__ __launch_bounds__(256) void gemm_score(const float* __restrict__ A,   // h3
                                                  const float* __restrict__ mu,
                                                  const float* __restrict__ inv,
                                                  const float* __restrict__ Bw,
                                                  const float* __restrict__ b1,
                                                  const float* __restrict__ px,
                                                  const float* __restrict__ mu_px,
                                                  const float* __restrict__ inv_px,
                                                  const float* __restrict__ attn_w,
                                                  float* __restrict__ ph,
                                                  float* __restrict__ lsc) {
    __shared__ __align__(16) float As[16][64];
    __shared__ __align__(16) float Bs[16][128];
    __shared__ float red[64][17];
    int tid = threadIdx.x;
    int m0 = blockIdx.x * 64;
    int lr = tid >> 2, lc = (tid & 3) << 2;
    int lrB = tid >> 1, lcB = (tid & 1) << 3;
    int tr = tid >> 4, tc = tid & 15;
    int tm = tr << 2, tn = tc << 3;
    float acc[4][8] = {};
    int bidx = (m0 + lr) >> 8;
    const float* Arow = A + (size_t)(m0 + lr) * 128 + lc;
    const float* mup = mu + bidx * 128 + lc;
    const float* ivp = inv + bidx * 128 + lc;
    const float* Brow = Bw + (size_t)lrB * 128 + lcB;
    for (int kb = 0; kb < 128; kb += 16) {
        float4 av = *(const float4*)(Arow + kb);
        float4 m4 = *(const float4*)(mup + kb);
        float4 i4 = *(const float4*)(ivp + kb);
        av.x = (av.x - m4.x) * i4.x; av.y = (av.y - m4.y) * i4.y;
        av.z = (av.z - m4.z) * i4.z; av.w = (av.w - m4.w) * i4.w;
        float4 bv0 = *(const float4*)(Brow + kb);
        float4 bv1 = *(const float4*)(Brow + kb + 4);
        __syncthreads();
        As[lc + 0][lr] = av.x; As[lc + 1][lr] = av.y; As[lc + 2][lr] = av.z; As[lc + 3][lr] = av.w;
        Bs[lcB + 0][lrB] = bv0.x; Bs[lcB + 1][lrB] = bv0.y; Bs[lcB + 2][lrB] = bv0.z; Bs[lcB + 3][lrB] = bv0.w;
        Bs[lcB + 4][lrB] = bv1.x; Bs[lcB + 5][lrB] = bv1.y; Bs[lcB + 6][lrB] = bv1.z; Bs[lcB + 7][lrB] = bv1.w;
        __syncthreads();
#pragma unroll
        for (int k = 0; k < 16; k++) {
            float ar[4], br[8];
#pragma unroll
            for (int i = 0; i < 4; i++) ar[i] = As[k][tm + i];
#pragma unroll
            for (int j = 0; j < 8; j++) br[j] = Bs[k][tn + j];
#pragma unroll
            for (int i = 0; i < 4; i++)
#pragma unroll
                for (int j = 0; j < 8; j++)
                    acc[i][j] = fmaf(ar[i], br[j], acc[i][j]);
        }
    }
    float spart[4];
#pragma unroll
    for (int i = 0; i < 4; i++) {
        int row = m0 + tm + i;
        int bb = row >> 8;
        float sp = 0.f;
#pragma unroll
        for (int j = 0; j < 8; j++) {
            int col = tn + j;
            float val = acc[i][j] + b1[col];
            ph[(size_t)row * 128 + col] = val;
            float inx = (px[(size_t)row * 128 + col] - mu_px[bb * 128 + col]) * inv_px[bb * 128 + col];
            sp = fmaf(tanh_(val + inx), attn_w[col], sp);
        }
        spart[i] = sp;
    }
    __syncthreads();
#pragma unroll
    for (int i = 0; i < 4; i++) red[tm + i][tc] = spart[i];
    __syncthreads();
    if (tid < 64) {
        float s = 0.f;
#pragma unroll
        for (int j = 0; j < 16; j++) s += red[tid][j];
        lsc[m0 + tid] = s;
    }
}

// ---------------- tail4: softmax + att map quarter + classify (64 WGs) -------------
__global__ __launch_bounds__(256) void tail4(const float* __restrict__ lsc,
                                             const float* __restrict__ ph,
                                             const float* __restrict__ fc_w,
                                             const float* __restrict__ fc_b,
                                             float* __restrict__ out,
                                             float* __restrict__ out_att) {
    int b = blockIdx.x >> 2, qt = blockIdx.x & 3;
    int tid = threadIdx.x;
    int h = tid & 127, st = tid >> 7;
    const float* phb = ph + (size_t)b * T_ * H_;
    __shared__ float tmp[256], wsh[256], ls[256];
    float v = lsc[b * 256 + tid];
    tmp[tid] = v; __syncthreads();
    for (int off = 128; off > 0; off >>= 1) { if (tid < off) tmp[tid] = fmaxf(tmp[tid], tmp[tid + off]); __syncthreads(); }
    float mx = tmp[0]; __syncthreads();
    float e = __expf(v - mx);
    tmp[tid] = e; __syncthreads();
    for (int off = 128; off > 0; off >>= 1) { if (tid < off) tmp[tid] += tmp[tid + off]; __syncthreads(); }
    wsh[tid] = e / tmp[0];
    __syncthreads();
    {   // attention-map quarter: t rows [qt*64, qt*64+64)
        float* ob = out_att + (size_t)b * T_ * D_;
        const float invD = 1.f / (float)D_;
        int base = qt * 64 * 128;
        for (int i = tid; i < 64 * 128; i += 256) ob[base + i] = wsh[(base + i) >> 7] * invD;
    }
    if (qt == 0) {   // context + FC
        float acc = 0.f;
        for (int t = st; t < T_; t += 2) acc = fmaf(phb[t * 128 + h], wsh[t], acc);
        ls[tid] = acc;
        __syncthreads();
        if (tid < 128) ls[tid] = ls[tid] + ls[tid + 128];
        __syncthreads();
        if (tid < NC_) {
            float s = fc_b[tid];
            const float* fw = fc_w + tid * 128;
            for (int k = 0; k < 128; k++) s = fmaf(ls[k], fw[k], s);
            out[b * NC_ + tid] = s;
        }
    }
}

// ---------------- launcher ----------------
extern "C" void kernel_launch(void* const* d_in, const int* in_sizes, int n_in,
                              void* d_out, int out_size, void* d_ws, size_t ws_size,
                              hipStream_t stream) {
    const float* x        = (const float*)d_in[0];
    const float* Wih      = (const float*)d_in[1];
    const float* Whh      = (const float*)d_in[2];
    const float* bih      = (const float*)d_in[3];
    const float* bhh      = (const float*)d_in[4];
    const float* proj_h_w = (const float*)d_in[5];
    const float* proj_h_b = (const float*)d_in[6];
    const float* proj_x_w = (const float*)d_in[7];
    const float* proj_x_b = (const float*)d_in[8];
    const float* attn_w   = (const float*)d_in[9];
    const float* fc_w     = (const float*)d_in[10];
    const float* fc_b     = (const float*)d_in[11];
    float* out = (float*)d_out;

    float* ws = (float*)d_ws;
    const size_t NTD = (size_t)B_ * T_ * D_;       // 524288
    float* h_glob = ws;                            // 4*NTD
    float* ring   = h_glob + 4 * NTD;              // 4*NTD
    float* px     = ring + 4 * NTD;                // 1*NTD
    float* smalls = px + NTD;
    float* psum   = smalls;                        // 256*128
    float* psq    = psum + 32768;                  // 256*128
    float* mu_bd  = psq + 32768;
    float* invn   = mu_bd + 2048;
    float* mu_ln  = invn + 2048;
    float* inv_ln = mu_ln + 2048;
    float* mu_px  = inv_ln + 2048;
    float* inv_px = mu_px + 2048;
    float* lsc    = inv_px + 2048;
    int*   flags  = (int*)(lsc + 4096);
    int*   flag_h = flags;                         // [64]
    int*   flag_g = flags + 64;                    // [64]
    float* ph = h_glob;                            // post-scan reuse
    const float* h3 = h_glob + 3 * NTD;

    hipMemsetAsync((void*)flags, 0, 128 * sizeof(int), stream);

    // head: parallel partial stats + fused-normalization factors (tiny)
    stats_bd<<<256, 512, 0, stream>>>(x, psum, psq);
    stats_norm<<<1, 128, 0, stream>>>(psum, psq, mu_bd, invn);

    // the whole pipeline-shaped middle: 4-layer LSTM + all riders
    scan_pipe6<<<160, 512, 0, stream>>>(x, Wih, Whh, bih, bhh,
                                        proj_x_w, proj_x_b, mu_bd, invn,
                                        h_glob, ring, px, mu_px, inv_px,
                                        mu_ln, inv_ln, flag_h, flag_g);

    // ph = IN(h3) @ proj_h_w^T + b, fused with attention scores
    gemm_score<<<64, 256, 0, stream>>>(h3, mu_ln, inv_ln, proj_h_w, proj_h_b,
                                       px, mu_px, inv_px, attn_w, ph, lsc);

    // softmax + attention map + classify (4 WGs per batch)
    tail4<<<64, 256, 0, stream>>>(lsc, ph, fc_w, fc_b, out, out + B_ * NC_);
}

// Round 16
// 462.674 us; speedup vs baseline: 1.6204x; 1.0508x over previous
//
#include <hip/hip_runtime.h>
#include <math.h>
#include <cstddef>

#define B_ 16
#define T_ 256
#define D_ 128
#define H_ 128
#define L_ 4
#define G_ 512          // 4*H
#define NC_ 10
#define EPS_ 1e-5f
#define C_ 16           // pipeline chunk (timesteps per flag)
#define NCHUNK_ (T_ / C_)

// padded LDS row: +4 floats per 32 -> 144-float rows; quarter q at q*36 floats
#define HROW_ 144
#define HOFF(k) ((k) + (((k) >> 5) << 2))

typedef float f4v __attribute__((ext_vector_type(4)));

// 8 x global_load_dwordx4 -> 32 floats resident (compiler cannot remat asm)
#define LOAD_W8(w, base)                                                   \
    asm volatile(                                                          \
        "global_load_dwordx4 %0, %8, off\n\t"                             \
        "global_load_dwordx4 %1, %8, off offset:16\n\t"                   \
        "global_load_dwordx4 %2, %8, off offset:32\n\t"                   \
        "global_load_dwordx4 %3, %8, off offset:48\n\t"                   \
        "global_load_dwordx4 %4, %8, off offset:64\n\t"                   \
        "global_load_dwordx4 %5, %8, off offset:80\n\t"                   \
        "global_load_dwordx4 %6, %8, off offset:96\n\t"                   \
        "global_load_dwordx4 %7, %8, off offset:112\n\t"                  \
        "s_waitcnt vmcnt(0)"                                               \
        : "=&v"(w[0]), "=&v"(w[1]), "=&v"(w[2]), "=&v"(w[3]),              \
          "=&v"(w[4]), "=&v"(w[5]), "=&v"(w[6]), "=&v"(w[7])               \
        : "v"(base)                                                        \
        : "memory")

// 32-k partial dot against pre-loaded h registers (params avoid x/y/z/w tokens)
#define DOT32R(dst_, warr_, hvarr_)                                        \
    {                                                                      \
        float d0_ = 0.f, d1_ = 0.f;                                        \
        _Pragma("unroll")                                                  \
        for (int j_ = 0; j_ < 8; j_++) {                                   \
            d0_ = fmaf(warr_[j_].x, hvarr_[j_].x, d0_);                    \
            d1_ = fmaf(warr_[j_].y, hvarr_[j_].y, d1_);                    \
            d0_ = fmaf(warr_[j_].z, hvarr_[j_].z, d0_);                    \
            d1_ = fmaf(warr_[j_].w, hvarr_[j_].w, d1_);                    \
        }                                                                  \
        dst_ = d0_ + d1_;                                                  \
    }

// ---------------- device helpers ----------------
__device__ __forceinline__ float sigmoid_(float x) {
    x = fminf(fmaxf(x, -30.f), 30.f);
    return 1.f / (1.f + __expf(-x));
}
__device__ __forceinline__ float tanh_(float x) {
    float ax = fminf(fabsf(x), 15.f);
    float e = __expf(2.f * ax);
    float t = 1.f - 2.f / (e + 1.f);
    return copysignf(t, x);
}
__device__ __forceinline__ void wait_ge_(int* p, int v) {
    if (__hip_atomic_load(p, __ATOMIC_RELAXED, __HIP_MEMORY_SCOPE_AGENT) < v) {
        do { __builtin_amdgcn_s_sleep(1); }
        while (__hip_atomic_load(p, __ATOMIC_RELAXED, __HIP_MEMORY_SCOPE_AGENT) < v);
    }
    (void)__hip_atomic_load(p, __ATOMIC_ACQUIRE, __HIP_MEMORY_SCOPE_AGENT);
}
__device__ __forceinline__ void ast_(float* p, float v) {
    __hip_atomic_store(p, v, __ATOMIC_RELAXED, __HIP_MEMORY_SCOPE_AGENT);
}
__device__ __forceinline__ float ald_(const float* p) {
    return __hip_atomic_load(p, __ATOMIC_RELAXED, __HIP_MEMORY_SCOPE_AGENT);
}

// ---------------- head: per-(b,strip) partial stats (256 WGs) ----------------
__global__ __launch_bounds__(512) void stats_bd(const float* __restrict__ x,
                                                float* __restrict__ psum,
                                                float* __restrict__ psq) {
    int blk = blockIdx.x;                 // b*16 + strip
    int b = blk >> 4, strip = blk & 15;
    int tid = threadIdx.x;
    int d = tid & 127, r = tid >> 7;
    const float* xb = x + (size_t)b * T_ * D_ + (size_t)strip * 16 * D_;
    float s = 0.f, q = 0.f;
    for (int t = r; t < 16; t += 4) {
        float v = xb[t * D_ + d];
        s += v; q += v * v;
    }
    __shared__ float ls[512], lq[512];
    ls[tid] = s; lq[tid] = q;
    __syncthreads();
    if (r == 0) {
        s = ls[d] + ls[d + 128] + ls[d + 256] + ls[d + 384];
        q = lq[d] + lq[d + 128] + lq[d + 256] + lq[d + 384];
        psum[blk * 128 + d] = s;
        psq[blk * 128 + d] = q;
    }
}

__global__ __launch_bounds__(128) void stats_norm(const float* __restrict__ psum,
                                                  const float* __restrict__ psq,
                                                  float* __restrict__ mu_bd,
                                                  float* __restrict__ invn) {
    int d = threadIdx.x;
    float S = 0.f, Q = 0.f;
    float sb[16], qb[16];
    for (int b = 0; b < 16; b++) {
        float s = 0.f, q = 0.f;
        for (int st = 0; st < 16; st++) {
            s += psum[(b * 16 + st) * 128 + d];
            q += psq[(b * 16 + st) * 128 + d];
        }
        sb[b] = s; qb[b] = q; S += s; Q += q;
    }
    float n = (float)(B_ * T_);
    float m = S / n;
    float varu = (Q - n * m * m) / (n - 1.f);
    float sd = sqrtf(fmaxf(varu, 0.f)) + EPS_;
    for (int b = 0; b < 16; b++) {
        float mu = sb[b] * (1.f / T_);
        float varT = qb[b] * (1.f / T_) - mu * mu;
        mu_bd[b * 128 + d] = mu;
        invn[b * 128 + d] = rsqrtf(fmaxf(varT, 0.f) + EPS_ * sd * sd);
    }
}

// ---------------- megascan: scan + all riders + score/tail ----------------
// 224 WGs x 512 thr (waves_per_eu(2,2) => 1 WG/CU cap => all co-resident):
//   wg[0..63]    rec(l,b)                  (R15 structure, unchanged)
//   wg[64..127]  xproj(l=0..3,b)           (unchanged)
//   wg[128..143] px rider (+ flag_px[b] publish)
//   wg[144..159] h3-stats rider (+ flag_ln[b] publish)
//   wg[160..223] score/tail rider: ph tile GEMM + scores; per-batch counter
//                sync; softmax + attention-map quarter; qt==0 context+FC
__global__ __attribute__((amdgpu_waves_per_eu(2, 2))) __launch_bounds__(512)
void megascan(const float* __restrict__ x,
              const float* __restrict__ Wih, const float* __restrict__ Whh,
              const float* __restrict__ bih, const float* __restrict__ bhh,
              const float* __restrict__ proj_x_w, const float* __restrict__ proj_x_b,
              const float* __restrict__ proj_h_w, const float* __restrict__ proj_h_b,
              const float* __restrict__ attn_w,
              const float* __restrict__ fc_w, const float* __restrict__ fc_b,
              const float* __restrict__ mu_bd, const float* __restrict__ invn,
              float* __restrict__ h_glob,        // [L][B][T][H]; layer0 becomes ph
              float* __restrict__ ring,          // [4][B][4][C_][G]
              float* __restrict__ px,            // [B][T][H]
              float* __restrict__ mu_px, float* __restrict__ inv_px,
              float* __restrict__ mu_ln, float* __restrict__ inv_ln,
              float* __restrict__ lsc,           // [B][T]
              float* __restrict__ out, float* __restrict__ out_att,
              int* __restrict__ flag_h,          // [4][B]
              int* __restrict__ flag_g,          // [4][B]
              int* __restrict__ flag_px,         // [B]
              int* __restrict__ flag_ln,         // [B]
              int* __restrict__ cnt) {           // [B]
    const int wg = blockIdx.x;
    const int tid = threadIdx.x;
    __shared__ __align__(16) float shbuf[16 * HROW_];   // scan/rider roles
    __shared__ __align__(16) float sAs[64][32];         // score role
    __shared__ __align__(16) float sBs[32][132];
    __shared__ float sred[64][33];
    __shared__ float stmp[256], swsh[256], sctx[512];

    if (wg < 64) {
        // ======== recurrent consumer (l, b) ========
        const int r = tid >> 2, q = tid & 3;
        const int l = wg >> 4, b = wg & 15;
        f4v w0[8], w1[8], w2[8], w3[8];
        const float* wl = Whh + (size_t)l * G_ * 128;
        LOAD_W8(w0, wl + ((size_t)(0 * 128 + r)) * 128 + q * 32);
        LOAD_W8(w1, wl + ((size_t)(1 * 128 + r)) * 128 + q * 32);
        LOAD_W8(w2, wl + ((size_t)(2 * 128 + r)) * 128 + q * 32);
        LOAD_W8(w3, wl + ((size_t)(3 * 128 + r)) * 128 + q * 32);
        float c = 0.f;
        if (tid < HROW_) shbuf[tid] = 0.f;
        const float* rsl = ring + ((size_t)l * 16 + b) * (4 * C_ * G_);
        float* hob = h_glob + ((size_t)l * 16 + b) * T_ * 128;
        int* fg = flag_g + l * 16 + b;
        int* fh = flag_h + l * 16 + b;
        float hreg[C_];
        __syncthreads();

        for (int k = 0; k < NCHUNK_; k++) {
            if (tid == 0) wait_ge_(fg, k + 1);
            __syncthreads();
#pragma unroll
            for (int half = 0; half < 2; half++) {
                float p0[8], p1[8], p2[8], p3[8];
#pragma unroll
                for (int s8 = 0; s8 < 8; s8++) {
                    int s = half * 8 + s8;
                    const float* gp = rsl + ((size_t)(k & 3) * C_ + s) * G_;
                    p0[s8] = ald_(gp + r);
                    p1[s8] = ald_(gp + 128 + r);
                    p2[s8] = ald_(gp + 256 + r);
                    p3[s8] = ald_(gp + 384 + r);
                }
#pragma unroll
                for (int s8 = 0; s8 < 8; s8++) {
                    int s = half * 8 + s8;
                    int t = k * C_ + s;
                    const f4v* hb4 = (const f4v*)(shbuf + (t & 1) * HROW_ + q * 36);
                    f4v hv[8];
#pragma unroll
                    for (int j = 0; j < 8; j++) hv[j] = hb4[j];
                    float zi, zf, zg, zo;
                    DOT32R(zi, w0, hv);
                    DOT32R(zf, w1, hv);
                    DOT32R(zg, w2, hv);
                    DOT32R(zo, w3, hv);
                    zi += __shfl_xor(zi, 1); zi += __shfl_xor(zi, 2);
                    zf += __shfl_xor(zf, 1); zf += __shfl_xor(zf, 2);
                    zg += __shfl_xor(zg, 1); zg += __shfl_xor(zg, 2);
                    zo += __shfl_xor(zo, 1); zo += __shfl_xor(zo, 2);
                    zi += p0[s8]; zf += p1[s8]; zg += p2[s8]; zo += p3[s8];
                    float ai = sigmoid_(zi), af = sigmoid_(zf);
                    float ag = tanh_(zg),    ao = sigmoid_(zo);
                    c = fmaf(af, c, ai * ag);
                    float hn = ao * tanh_(c);
                    if (q == 0) shbuf[((t + 1) & 1) * HROW_ + HOFF(r)] = hn;
                    hreg[s] = hn;
                    __syncthreads();
                }
            }
            if (q == 0) {
#pragma unroll
                for (int s = 0; s < C_; s++)
                    ast_(hob + (size_t)(k * C_ + s) * 128 + r, hreg[s]);
            }
            __syncthreads();
            if (tid == 0) __hip_atomic_store(fh, k + 1, __ATOMIC_RELEASE, __HIP_MEMORY_SCOPE_AGENT);
        }
    } else if (wg < 128) {
        // ======== xproj producer (layers 0..3) ========
        const int r = tid >> 2, q = tid & 3;
        const int l = (wg - 64) >> 4, b = (wg - 64) & 15;
        f4v w0[8], w1[8], w2[8], w3[8];
        const float* wl = Wih + (size_t)l * G_ * 128;
        LOAD_W8(w0, wl + ((size_t)(0 * 128 + r)) * 128 + q * 32);
        LOAD_W8(w1, wl + ((size_t)(1 * 128 + r)) * 128 + q * 32);
        LOAD_W8(w2, wl + ((size_t)(2 * 128 + r)) * 128 + q * 32);
        LOAD_W8(w3, wl + ((size_t)(3 * 128 + r)) * 128 + q * 32);
        float bs0 = bih[l * G_ + r] + bhh[l * G_ + r];
        float bs1 = bih[l * G_ + 128 + r] + bhh[l * G_ + 128 + r];
        float bs2 = bih[l * G_ + 256 + r] + bhh[l * G_ + 256 + r];
        float bs3 = bih[l * G_ + 384 + r] + bhh[l * G_ + 384 + r];
        const float* hsrc = (l > 0) ? h_glob + ((size_t)(l - 1) * 16 + b) * T_ * 128
                                    : x + (size_t)b * T_ * 128;
        float muk = 0.f, ivk = 1.f;
        if (l == 0) { muk = mu_bd[b * 128 + (tid & 127)]; ivk = invn[b * 128 + (tid & 127)]; }
        float* rout = ring + ((size_t)l * 16 + b) * (4 * C_ * G_);
        int* fhp = (l > 0) ? flag_h + (l - 1) * 16 + b : flag_h;
        int* fhme = flag_h + l * 16 + b;
        int* fgo = flag_g + l * 16 + b;

        for (int k = 0; k < NCHUNK_; k++) {
            if (tid == 0) {
                if (l > 0) wait_ge_(fhp, k + 1);
                if (k >= 4) wait_ge_(fhme, k - 3);
            }
            __syncthreads();
#pragma unroll
            for (int i = 0; i < 4; i++) {
                int idx = i * 512 + tid;
                float v;
                if (l == 0) {
                    v = hsrc[(size_t)k * C_ * 128 + idx];
                    v = (v - muk) * ivk;
                } else {
                    v = ald_(hsrc + (size_t)k * C_ * 128 + idx);
                }
                shbuf[(idx >> 7) * HROW_ + HOFF(idx & 127)] = v;
            }
            __syncthreads();
#pragma unroll
            for (int s = 0; s < C_; s++) {
                const f4v* hb4 = (const f4v*)(shbuf + s * HROW_ + q * 36);
                f4v hv[8];
#pragma unroll
                for (int j = 0; j < 8; j++) hv[j] = hb4[j];
                float z0, z1, z2, z3;
                DOT32R(z0, w0, hv);
                DOT32R(z1, w1, hv);
                DOT32R(z2, w2, hv);
                DOT32R(z3, w3, hv);
                z0 += __shfl_xor(z0, 1); z0 += __shfl_xor(z0, 2);
                z1 += __shfl_xor(z1, 1); z1 += __shfl_xor(z1, 2);
                z2 += __shfl_xor(z2, 1); z2 += __shfl_xor(z2, 2);
                z3 += __shfl_xor(z3, 1); z3 += __shfl_xor(z3, 2);
                if (q == 0) {
                    float* ro = rout + ((size_t)(k & 3) * C_ + s) * G_;
                    ast_(ro + r, z0 + bs0);
                    ast_(ro + 128 + r, z1 + bs1);
                    ast_(ro + 256 + r, z2 + bs2);
                    ast_(ro + 384 + r, z3 + bs3);
                }
            }
            __syncthreads();
            if (tid == 0) __hip_atomic_store(fgo, k + 1, __ATOMIC_RELEASE, __HIP_MEMORY_SCOPE_AGENT);
        }
    } else if (wg < 144) {
        // ======== px rider: px[b] = norm(x[b]) @ proj_x_w^T + b; + IN stats ========
        const int b = wg - 128;
        const int h = tid & 127, tq = tid >> 7;
        f4v w0[8], w1[8], w2[8], w3[8];
        LOAD_W8(w0, proj_x_w + (size_t)h * 128 + 0);
        LOAD_W8(w1, proj_x_w + (size_t)h * 128 + 32);
        LOAD_W8(w2, proj_x_w + (size_t)h * 128 + 64);
        LOAD_W8(w3, proj_x_w + (size_t)h * 128 + 96);
        float bsx = proj_x_b[h];
        float muk = mu_bd[b * 128 + h], ivk = invn[b * 128 + h];
        const float* xb = x + (size_t)b * T_ * 128;
        float* pxb = px + (size_t)b * T_ * 128;
        float sacc = 0.f, qacc = 0.f;

        for (int blk = 0; blk < 16; blk++) {
            int t0 = blk * 16;
            __syncthreads();
#pragma unroll
            for (int j = 0; j < 4; j++) {
                int tt = tq * 4 + j;
                float v = xb[(size_t)(t0 + tt) * 128 + h];
                shbuf[tt * HROW_ + HOFF(h)] = (v - muk) * ivk;
            }
            __syncthreads();
#pragma unroll
            for (int j = 0; j < 4; j++) {
                int tt = tq * 4 + j;
                const float* row = shbuf + tt * HROW_;
                f4v hv[8];
                float p0, p1, p2, p3;
                const f4v* r4 = (const f4v*)(row + 0 * 36);
#pragma unroll
                for (int u = 0; u < 8; u++) hv[u] = r4[u];
                DOT32R(p0, w0, hv);
                r4 = (const f4v*)(row + 1 * 36);
#pragma unroll
                for (int u = 0; u < 8; u++) hv[u] = r4[u];
                DOT32R(p1, w1, hv);
                r4 = (const f4v*)(row + 2 * 36);
#pragma unroll
                for (int u = 0; u < 8; u++) hv[u] = r4[u];
                DOT32R(p2, w2, hv);
                r4 = (const f4v*)(row + 3 * 36);
#pragma unroll
                for (int u = 0; u < 8; u++) hv[u] = r4[u];
                DOT32R(p3, w3, hv);
                float val = (p0 + p1) + (p2 + p3) + bsx;
                ast_(pxb + (size_t)(t0 + tt) * 128 + h, val);
                sacc += val; qacc += val * val;
            }
        }
        __syncthreads();
        shbuf[tq * 128 + h] = sacc;
        shbuf[512 + tq * 128 + h] = qacc;
        __syncthreads();
        if (tq == 0) {
            float s = shbuf[h] + shbuf[128 + h] + shbuf[256 + h] + shbuf[384 + h];
            float qq = shbuf[512 + h] + shbuf[640 + h] + shbuf[768 + h] + shbuf[896 + h];
            float m = s * (1.f / T_);
            float v = qq * (1.f / T_) - m * m;
            ast_(mu_px + b * 128 + h, m);
            ast_(inv_px + b * 128 + h, rsqrtf(fmaxf(v, 0.f) + EPS_));
        }
        __syncthreads();   // drains vmcnt: px + stats visible
        if (tid == 0) __hip_atomic_store(flag_px + b, 1, __ATOMIC_RELEASE, __HIP_MEMORY_SCOPE_AGENT);
    } else if (wg < 160) {
        // ======== h3-stats rider: IN stats of layer-3 h, chunk-incremental ========
        const int b = wg - 144;
        const int h = tid & 127, st = tid >> 7;
        const float* hsrc = h_glob + ((size_t)3 * 16 + b) * T_ * 128;
        int* f3 = flag_h + 3 * 16 + b;
        float s = 0.f, q = 0.f;
        for (int k = 0; k < NCHUNK_; k++) {
            if (tid == 0) wait_ge_(f3, k + 1);
            __syncthreads();
#pragma unroll
            for (int j = 0; j < 4; j++) {
                int tt = st * 4 + j;
                float v = ald_(hsrc + (size_t)(k * C_ + tt) * 128 + h);
                s += v; q += v * v;
            }
        }
        shbuf[st * 128 + h] = s;
        shbuf[512 + st * 128 + h] = q;
        __syncthreads();
        if (st == 0) {
            float ss = shbuf[h] + shbuf[128 + h] + shbuf[256 + h] + shbuf[384 + h];
            float qq = shbuf[512 + h] + shbuf[640 + h] + shbuf[768 + h] + shbuf[896 + h];
            float m = ss * (1.f / T_);
            float v = qq * (1.f / T_) - m * m;
            ast_(mu_ln + b * 128 + h, m);
            ast_(inv_ln + b * 128 + h, rsqrtf(fmaxf(v, 0.f) + EPS_));
        }
        __syncthreads();   // drains vmcnt
        if (tid == 0) __hip_atomic_store(flag_ln + b, 1, __ATOMIC_RELEASE, __HIP_MEMORY_SCOPE_AGENT);
    } else {
        // ======== score/tail rider: blk in [0,64), b = blk>>2, qt = blk&3 ========
        const int blk = wg - 160;
        const int b = blk >> 2, qt = blk & 3;
        const int m0 = qt * 64;                  // t-row offset within batch
        if (tid == 0) { wait_ge_(flag_px + b, 1); wait_ge_(flag_ln + b, 1); }
        __syncthreads();                          // acquire L1-inv applied CU-wide

        const float* h3b = h_glob + ((size_t)3 * 16 + b) * T_ * 128;
        float* phg = h_glob;                      // ph aliases layer-0 h (all readers done)
        const int lr = tid >> 3, lc = (tid & 7) << 2;   // A staging
        const int nB = tid >> 2, k0B = (tid & 3) << 3;  // B staging
        const int tm = (tid >> 5) << 2, tn = (tid & 31) << 2;
        float acc[4][4] = {};
        const float* mup = mu_ln + b * 128;
        const float* ivp = inv_ln + b * 128;
        for (int kb = 0; kb < 128; kb += 32) {
            float4 av = *(const float4*)(h3b + (size_t)(m0 + lr) * 128 + kb + lc);
            float4 m4 = *(const float4*)(mup + kb + lc);
            float4 i4 = *(const float4*)(ivp + kb + lc);
            av.x = (av.x - m4.x) * i4.x; av.y = (av.y - m4.y) * i4.y;
            av.z = (av.z - m4.z) * i4.z; av.w = (av.w - m4.w) * i4.w;
            float4 bv0 = *(const float4*)(proj_h_w + (size_t)nB * 128 + kb + k0B);
            float4 bv1 = *(const float4*)(proj_h_w + (size_t)nB * 128 + kb + k0B + 4);
            __syncthreads();
            *(float4*)&sAs[lr][lc] = av;
            sBs[k0B + 0][nB] = bv0.x; sBs[k0B + 1][nB] = bv0.y;
            sBs[k0B + 2][nB] = bv0.z; sBs[k0B + 3][nB] = bv0.w;
            sBs[k0B + 4][nB] = bv1.x; sBs[k0B + 5][nB] = bv1.y;
            sBs[k0B + 6][nB] = bv1.z; sBs[k0B + 7][nB] = bv1.w;
            __syncthreads();
#pragma unroll
            for (int k4 = 0; k4 < 8; k4++) {
                f4v a4[4];
#pragma unroll
                for (int i = 0; i < 4; i++) a4[i] = *(const f4v*)&sAs[tm + i][k4 * 4];
#pragma unroll
                for (int kk = 0; kk < 4; kk++) {
                    f4v b4 = *(const f4v*)&sBs[k4 * 4 + kk][tn];
#pragma unroll
                    for (int i = 0; i < 4; i++) {
                        acc[i][0] = fmaf(a4[i][kk], b4.x, acc[i][0]);
                        acc[i][1] = fmaf(a4[i][kk], b4.y, acc[i][1]);
                        acc[i][2] = fmaf(a4[i][kk], b4.z, acc[i][2]);
                        acc[i][3] = fmaf(a4[i][kk], b4.w, acc[i][3]);
                    }
                }
            }
        }
        // epilogue: ph + score partials
        float spart[4];
#pragma unroll
        for (int i = 0; i < 4; i++) {
            int t = m0 + tm + i;
            size_t prow = ((size_t)b * 256 + t) * 128;
            float sp = 0.f;
#pragma unroll
            for (int j = 0; j < 4; j++) {
                int col = tn + j;
                float val = acc[i][j] + proj_h_b[col];
                ast_(phg + prow + col, val);
                float inx = (ald_(px + prow + col) - ald_(mu_px + b * 128 + col))
                            * ald_(inv_px + b * 128 + col);
                sp = fmaf(tanh_(val + inx), attn_w[col], sp);
            }
            spart[i] = sp;
        }
        __syncthreads();
#pragma unroll
        for (int i = 0; i < 4; i++) sred[tm + i][tid & 31] = spart[i];
        __syncthreads();
        if (tid < 64) {
            float s = 0.f;
#pragma unroll
            for (int j = 0; j < 32; j++) s += sred[tid][j];
            ast_(lsc + b * 256 + m0 + tid, s);
        }
        __syncthreads();   // drains vmcnt: ph + lsc visible
        if (tid == 0) {
            (void)__hip_atomic_fetch_add(cnt + b, 1, __ATOMIC_ACQ_REL, __HIP_MEMORY_SCOPE_AGENT);
            wait_ge_(cnt + b, 4);
        }
        __syncthreads();
        // softmax over lsc[b][0..255] (redundant per block, cheap)
        float v = 0.f;
        if (tid < 256) { v = ald_(lsc + b * 256 + tid); stmp[tid] = v; }
        __syncthreads();
        for (int off = 128; off > 0; off >>= 1) {
            if (tid < off) stmp[tid] = fmaxf(stmp[tid], stmp[tid + off]);
            __syncthreads();
        }
        float mx = stmp[0];
        __syncthreads();
        float e = (tid < 256) ? __expf(v - mx) : 0.f;
        if (tid < 256) stmp[tid] = e;
        __syncthreads();
        for (int off = 128; off > 0; off >>= 1) {
            if (tid < off) stmp[tid] += stmp[tid + off];
            __syncthreads();
        }
        float tot = stmp[0];
        __syncthreads();
        if (tid < 256) swsh[tid] = e / tot;
        __syncthreads();
        {   // attention-map quarter (alpha = softmax_t / D, constant across d)
            float* ob = out_att + (size_t)b * T_ * D_ + (size_t)m0 * 128;
            const float invD = 1.f / (float)D_;
            for (int i = tid; i < 64 * 128; i += 512)
                ob[i] = swsh[m0 + (i >> 7)] * invD;
        }
        if (qt == 0) {   // context + FC
            int h = tid & 127, st = tid >> 7;
            float a = 0.f;
            for (int tt = st * 64; tt < st * 64 + 64; tt++)
                a = fmaf(phg[((size_t)b * 256 + tt) * 128 + h], swsh[tt], a);
            sctx[st * 128 + h] = a;
            __syncthreads();
            if (tid < 128) sctx[tid] = sctx[tid] + sctx[128 + tid] + sctx[256 + tid] + sctx[384 + tid];
            __syncthreads();
            if (tid < NC_) {
                float s = fc_b[tid];
                const float* fw = fc_w + tid * 128;
                for (int k = 0; k < 128; k++) s = fmaf(sctx[k], fw[k], s);
                out[b * NC_ + tid] = s;
            }
        }
    }
}

// ---------------- launcher ----------------
extern "C" void kernel_launch(void* const* d_in, const int* in_sizes, int n_in,
                              void* d_out, int out_size, void* d_ws, size_t ws_size,
                              hipStream_t stream) {
    const float* x        = (const float*)d_in[0];
    const float* Wih      = (const float*)d_in[1];
    const float* Whh      = (const float*)d_in[2];
    const float* bih      = (const float*)d_in[3];
    const float* bhh      = (const float*)d_in[4];
    const float* proj_h_w = (const float*)d_in[5];
    const float* proj_h_b = (const float*)d_in[6];
    const float* proj_x_w = (const float*)d_in[7];
    const float* proj_x_b = (const float*)d_in[8];
    const float* attn_w   = (const float*)d_in[9];
    const float* fc_w     = (const float*)d_in[10];
    const float* fc_b     = (const float*)d_in[11];
    float* out = (float*)d_out;

    float* ws = (float*)d_ws;
    const size_t NTD = (size_t)B_ * T_ * D_;       // 524288
    float* h_glob = ws;                            // 4*NTD
    float* ring   = h_glob + 4 * NTD;              // 4*NTD
    float* px     = ring + 4 * NTD;                // 1*NTD
    float* smalls = px + NTD;
    float* psum   = smalls;                        // 256*128
    float* psq    = psum + 32768;                  // 256*128
    float* mu_bd  = psq + 32768;
    float* invn   = mu_bd + 2048;
    float* mu_ln  = invn + 2048;
    float* inv_ln = mu_ln + 2048;
    float* mu_px  = inv_ln + 2048;
    float* inv_px = mu_px + 2048;
    float* lsc    = inv_px + 2048;
    int*   flags  = (int*)(lsc + 4096);
    int*   flag_h  = flags;                        // [64]
    int*   flag_g  = flags + 64;                   // [64]
    int*   flag_px = flags + 128;                  // [16]
    int*   flag_ln = flags + 144;                  // [16]
    int*   cnt     = flags + 160;                  // [16]

    hipMemsetAsync((void*)flags, 0, 256 * sizeof(int), stream);

    // head: parallel partial stats + fused-normalization factors (tiny)
    stats_bd<<<256, 512, 0, stream>>>(x, psum, psq);
    stats_norm<<<1, 128, 0, stream>>>(psum, psq, mu_bd, invn);

    // everything else: 4-layer LSTM pipeline + px/h3 riders + score/tail riders
    megascan<<<224, 512, 0, stream>>>(x, Wih, Whh, bih, bhh,
                                      proj_x_w, proj_x_b, proj_h_w, proj_h_b,
                                      attn_w, fc_w, fc_b,
                                      mu_bd, invn, h_glob, ring, px,
                                      mu_px, inv_px, mu_ln, inv_ln,
                                      lsc, out, out + B_ * NC_,
                                      flag_h, flag_g, flag_px, flag_ln, cnt);
}

// Round 17
// 450.201 us; speedup vs baseline: 1.6653x; 1.0277x over previous
//
#include <hip/hip_runtime.h>
#include <math.h>
#include <cstddef>

#define B_ 16
#define T_ 256
#define D_ 128
#define H_ 128
#define L_ 4
#define G_ 512          // 4*H
#define NC_ 10
#define EPS_ 1e-5f
#define C_ 16           // pipeline chunk (timesteps per flag)
#define NCHUNK_ (T_ / C_)

// padded LDS row: +4 floats per 32 -> 144-float rows; quarter q at q*36 floats
#define HROW_ 144
#define HOFF(k) ((k) + (((k) >> 5) << 2))

typedef float f4v __attribute__((ext_vector_type(4)));

// 8 x global_load_dwordx4 -> 32 floats resident (compiler cannot remat asm)
#define LOAD_W8(w, base)                                                   \
    asm volatile(                                                          \
        "global_load_dwordx4 %0, %8, off\n\t"                             \
        "global_load_dwordx4 %1, %8, off offset:16\n\t"                   \
        "global_load_dwordx4 %2, %8, off offset:32\n\t"                   \
        "global_load_dwordx4 %3, %8, off offset:48\n\t"                   \
        "global_load_dwordx4 %4, %8, off offset:64\n\t"                   \
        "global_load_dwordx4 %5, %8, off offset:80\n\t"                   \
        "global_load_dwordx4 %6, %8, off offset:96\n\t"                   \
        "global_load_dwordx4 %7, %8, off offset:112\n\t"                  \
        "s_waitcnt vmcnt(0)"                                               \
        : "=&v"(w[0]), "=&v"(w[1]), "=&v"(w[2]), "=&v"(w[3]),              \
          "=&v"(w[4]), "=&v"(w[5]), "=&v"(w[6]), "=&v"(w[7])               \
        : "v"(base)                                                        \
        : "memory")

// 32-k partial dot against pre-loaded h registers (params avoid x/y/z/w tokens)
#define DOT32R(dst_, warr_, hvarr_)                                        \
    {                                                                      \
        float d0_ = 0.f, d1_ = 0.f;                                        \
        _Pragma("unroll")                                                  \
        for (int j_ = 0; j_ < 8; j_++) {                                   \
            d0_ = fmaf(warr_[j_].x, hvarr_[j_].x, d0_);                    \
            d1_ = fmaf(warr_[j_].y, hvarr_[j_].y, d1_);                    \
            d0_ = fmaf(warr_[j_].z, hvarr_[j_].z, d0_);                    \
            d1_ = fmaf(warr_[j_].w, hvarr_[j_].w, d1_);                    \
        }                                                                  \
        dst_ = d0_ + d1_;                                                  \
    }

// ---------------- device helpers ----------------
__device__ __forceinline__ float sigmoid_(float x) {
    x = fminf(fmaxf(x, -30.f), 30.f);
    return 1.f / (1.f + __expf(-x));
}
__device__ __forceinline__ float tanh_(float x) {
    float ax = fminf(fabsf(x), 15.f);
    float e = __expf(2.f * ax);
    float t = 1.f - 2.f / (e + 1.f);
    return copysignf(t, x);
}
__device__ __forceinline__ void wait_ge_(int* p, int v) {
    if (__hip_atomic_load(p, __ATOMIC_RELAXED, __HIP_MEMORY_SCOPE_AGENT) < v) {
        do { __builtin_amdgcn_s_sleep(1); }
        while (__hip_atomic_load(p, __ATOMIC_RELAXED, __HIP_MEMORY_SCOPE_AGENT) < v);
    }
    (void)__hip_atomic_load(p, __ATOMIC_ACQUIRE, __HIP_MEMORY_SCOPE_AGENT);
}
__device__ __forceinline__ void ast_(float* p, float v) {
    __hip_atomic_store(p, v, __ATOMIC_RELAXED, __HIP_MEMORY_SCOPE_AGENT);
}
__device__ __forceinline__ float ald_(const float* p) {
    return __hip_atomic_load(p, __ATOMIC_RELAXED, __HIP_MEMORY_SCOPE_AGENT);
}

// ---------------- megascan: EVERYTHING (stats + scan + riders + score/tail) -------
// 240 WGs x 512 thr (waves_per_eu(2,2) => 1 WG/CU cap => all 240 co-resident):
//   wg[0..63]    rec(l,b)
//   wg[64..127]  xproj(l=0..3,b): l==0 waits flag_norm[b] for factors
//   wg[128..143] px rider (waits flag_norm[b]) -> flag_px[b]
//   wg[144..159] h3-stats rider -> flag_ln[b]
//   wg[160..223] score/tail rider (4/batch): ph GEMM + scores; cnt sync;
//                softmax + att-map quarter; qt==0 context+FC
//   wg[224..239] input-stats rider: partials -> cnt_s barrier -> factors
//                -> flag_norm[b]
__global__ __attribute__((amdgpu_waves_per_eu(2, 2))) __launch_bounds__(512)
void megascan(const float* __restrict__ x,
              const float* __restrict__ Wih, const float* __restrict__ Whh,
              const float* __restrict__ bih, const float* __restrict__ bhh,
              const float* __restrict__ proj_x_w, const float* __restrict__ proj_x_b,
              const float* __restrict__ proj_h_w, const float* __restrict__ proj_h_b,
              const float* __restrict__ attn_w,
              const float* __restrict__ fc_w, const float* __restrict__ fc_b,
              float* __restrict__ mu_bd, float* __restrict__ invn,
              float* __restrict__ psumB, float* __restrict__ psqB,
              float* __restrict__ h_glob,        // [L][B][T][H]; layer0 becomes ph
              float* __restrict__ ring,          // [4][B][4][C_][G]
              float* __restrict__ px,            // [B][T][H]
              float* __restrict__ mu_px, float* __restrict__ inv_px,
              float* __restrict__ mu_ln, float* __restrict__ inv_ln,
              float* __restrict__ lsc,           // [B][T]
              float* __restrict__ out, float* __restrict__ out_att,
              int* __restrict__ flag_h,          // [4][B]
              int* __restrict__ flag_g,          // [4][B]
              int* __restrict__ flag_px,         // [B]
              int* __restrict__ flag_ln,         // [B]
              int* __restrict__ cnt,             // [B]
              int* __restrict__ flag_norm,       // [B]
              int* __restrict__ cnt_s) {         // [1]
    const int wg = blockIdx.x;
    const int tid = threadIdx.x;
    __shared__ __align__(16) float shbuf[16 * HROW_];   // scan/rider roles
    __shared__ __align__(16) float sAs[64][32];         // score role
    __shared__ __align__(16) float sBs[32][132];
    __shared__ float sred[64][33];
    __shared__ float stmp[256], swsh[256], sctx[512];
    __shared__ float smu[128], siv[128];

    if (wg < 64) {
        // ======== recurrent consumer (l, b) ========
        const int r = tid >> 2, q = tid & 3;
        const int l = wg >> 4, b = wg & 15;
        f4v w0[8], w1[8], w2[8], w3[8];
        const float* wl = Whh + (size_t)l * G_ * 128;
        LOAD_W8(w0, wl + ((size_t)(0 * 128 + r)) * 128 + q * 32);
        LOAD_W8(w1, wl + ((size_t)(1 * 128 + r)) * 128 + q * 32);
        LOAD_W8(w2, wl + ((size_t)(2 * 128 + r)) * 128 + q * 32);
        LOAD_W8(w3, wl + ((size_t)(3 * 128 + r)) * 128 + q * 32);
        float c = 0.f;
        if (tid < HROW_) shbuf[tid] = 0.f;
        const float* rsl = ring + ((size_t)l * 16 + b) * (4 * C_ * G_);
        float* hob = h_glob + ((size_t)l * 16 + b) * T_ * 128;
        int* fg = flag_g + l * 16 + b;
        int* fh = flag_h + l * 16 + b;
        float hreg[C_];
        __syncthreads();

        for (int k = 0; k < NCHUNK_; k++) {
            if (tid == 0) wait_ge_(fg, k + 1);
            __syncthreads();
#pragma unroll
            for (int half = 0; half < 2; half++) {
                float p0[8], p1[8], p2[8], p3[8];
#pragma unroll
                for (int s8 = 0; s8 < 8; s8++) {
                    int s = half * 8 + s8;
                    const float* gp = rsl + ((size_t)(k & 3) * C_ + s) * G_;
                    p0[s8] = ald_(gp + r);
                    p1[s8] = ald_(gp + 128 + r);
                    p2[s8] = ald_(gp + 256 + r);
                    p3[s8] = ald_(gp + 384 + r);
                }
#pragma unroll
                for (int s8 = 0; s8 < 8; s8++) {
                    int s = half * 8 + s8;
                    int t = k * C_ + s;
                    const f4v* hb4 = (const f4v*)(shbuf + (t & 1) * HROW_ + q * 36);
                    f4v hv[8];
#pragma unroll
                    for (int j = 0; j < 8; j++) hv[j] = hb4[j];
                    float zi, zf, zg, zo;
                    DOT32R(zi, w0, hv);
                    DOT32R(zf, w1, hv);
                    DOT32R(zg, w2, hv);
                    DOT32R(zo, w3, hv);
                    zi += __shfl_xor(zi, 1); zi += __shfl_xor(zi, 2);
                    zf += __shfl_xor(zf, 1); zf += __shfl_xor(zf, 2);
                    zg += __shfl_xor(zg, 1); zg += __shfl_xor(zg, 2);
                    zo += __shfl_xor(zo, 1); zo += __shfl_xor(zo, 2);
                    zi += p0[s8]; zf += p1[s8]; zg += p2[s8]; zo += p3[s8];
                    float ai = sigmoid_(zi), af = sigmoid_(zf);
                    float ag = tanh_(zg),    ao = sigmoid_(zo);
                    c = fmaf(af, c, ai * ag);
                    float hn = ao * tanh_(c);
                    if (q == 0) shbuf[((t + 1) & 1) * HROW_ + HOFF(r)] = hn;
                    hreg[s] = hn;
                    __syncthreads();
                }
            }
            if (q == 0) {
#pragma unroll
                for (int s = 0; s < C_; s++)
                    ast_(hob + (size_t)(k * C_ + s) * 128 + r, hreg[s]);
            }
            __syncthreads();
            if (tid == 0) __hip_atomic_store(fh, k + 1, __ATOMIC_RELEASE, __HIP_MEMORY_SCOPE_AGENT);
        }
    } else if (wg < 128) {
        // ======== xproj producer (layers 0..3) ========
        const int r = tid >> 2, q = tid & 3;
        const int l = (wg - 64) >> 4, b = (wg - 64) & 15;
        f4v w0[8], w1[8], w2[8], w3[8];
        const float* wl = Wih + (size_t)l * G_ * 128;
        LOAD_W8(w0, wl + ((size_t)(0 * 128 + r)) * 128 + q * 32);
        LOAD_W8(w1, wl + ((size_t)(1 * 128 + r)) * 128 + q * 32);
        LOAD_W8(w2, wl + ((size_t)(2 * 128 + r)) * 128 + q * 32);
        LOAD_W8(w3, wl + ((size_t)(3 * 128 + r)) * 128 + q * 32);
        float bs0 = bih[l * G_ + r] + bhh[l * G_ + r];
        float bs1 = bih[l * G_ + 128 + r] + bhh[l * G_ + 128 + r];
        float bs2 = bih[l * G_ + 256 + r] + bhh[l * G_ + 256 + r];
        float bs3 = bih[l * G_ + 384 + r] + bhh[l * G_ + 384 + r];
        const float* hsrc = (l > 0) ? h_glob + ((size_t)(l - 1) * 16 + b) * T_ * 128
                                    : x + (size_t)b * T_ * 128;
        float muk = 0.f, ivk = 1.f;
        if (l == 0) {
            if (tid == 0) wait_ge_(flag_norm + b, 1);
            __syncthreads();                       // acquire L1-inv CU-wide
            muk = mu_bd[b * 128 + (tid & 127)];    // plain after acquire
            ivk = invn[b * 128 + (tid & 127)];
        }
        float* rout = ring + ((size_t)l * 16 + b) * (4 * C_ * G_);
        int* fhp = (l > 0) ? flag_h + (l - 1) * 16 + b : flag_h;
        int* fhme = flag_h + l * 16 + b;
        int* fgo = flag_g + l * 16 + b;

        for (int k = 0; k < NCHUNK_; k++) {
            if (tid == 0) {
                if (l > 0) wait_ge_(fhp, k + 1);
                if (k >= 4) wait_ge_(fhme, k - 3);
            }
            __syncthreads();
#pragma unroll
            for (int i = 0; i < 4; i++) {
                int idx = i * 512 + tid;
                float v;
                if (l == 0) {
                    v = hsrc[(size_t)k * C_ * 128 + idx];
                    v = (v - muk) * ivk;
                } else {
                    v = ald_(hsrc + (size_t)k * C_ * 128 + idx);
                }
                shbuf[(idx >> 7) * HROW_ + HOFF(idx & 127)] = v;
            }
            __syncthreads();
#pragma unroll
            for (int s = 0; s < C_; s++) {
                const f4v* hb4 = (const f4v*)(shbuf + s * HROW_ + q * 36);
                f4v hv[8];
#pragma unroll
                for (int j = 0; j < 8; j++) hv[j] = hb4[j];
                float z0, z1, z2, z3;
                DOT32R(z0, w0, hv);
                DOT32R(z1, w1, hv);
                DOT32R(z2, w2, hv);
                DOT32R(z3, w3, hv);
                z0 += __shfl_xor(z0, 1); z0 += __shfl_xor(z0, 2);
                z1 += __shfl_xor(z1, 1); z1 += __shfl_xor(z1, 2);
                z2 += __shfl_xor(z2, 1); z2 += __shfl_xor(z2, 2);
                z3 += __shfl_xor(z3, 1); z3 += __shfl_xor(z3, 2);
                if (q == 0) {
                    float* ro = rout + ((size_t)(k & 3) * C_ + s) * G_;
                    ast_(ro + r, z0 + bs0);
                    ast_(ro + 128 + r, z1 + bs1);
                    ast_(ro + 256 + r, z2 + bs2);
                    ast_(ro + 384 + r, z3 + bs3);
                }
            }
            __syncthreads();
            if (tid == 0) __hip_atomic_store(fgo, k + 1, __ATOMIC_RELEASE, __HIP_MEMORY_SCOPE_AGENT);
        }
    } else if (wg < 144) {
        // ======== px rider: px[b] = norm(x[b]) @ proj_x_w^T + b; + IN stats ========
        const int b = wg - 128;
        const int h = tid & 127, tq = tid >> 7;
        f4v w0[8], w1[8], w2[8], w3[8];
        LOAD_W8(w0, proj_x_w + (size_t)h * 128 + 0);
        LOAD_W8(w1, proj_x_w + (size_t)h * 128 + 32);
        LOAD_W8(w2, proj_x_w + (size_t)h * 128 + 64);
        LOAD_W8(w3, proj_x_w + (size_t)h * 128 + 96);
        float bsx = proj_x_b[h];
        if (tid == 0) wait_ge_(flag_norm + b, 1);
        __syncthreads();
        float muk = mu_bd[b * 128 + h], ivk = invn[b * 128 + h];   // plain after acquire
        const float* xb = x + (size_t)b * T_ * 128;
        float* pxb = px + (size_t)b * T_ * 128;
        float sacc = 0.f, qacc = 0.f;

        for (int blk = 0; blk < 16; blk++) {
            int t0 = blk * 16;
            __syncthreads();
#pragma unroll
            for (int j = 0; j < 4; j++) {
                int tt = tq * 4 + j;
                float v = xb[(size_t)(t0 + tt) * 128 + h];
                shbuf[tt * HROW_ + HOFF(h)] = (v - muk) * ivk;
            }
            __syncthreads();
#pragma unroll
            for (int j = 0; j < 4; j++) {
                int tt = tq * 4 + j;
                const float* row = shbuf + tt * HROW_;
                f4v hv[8];
                float p0, p1, p2, p3;
                const f4v* r4 = (const f4v*)(row + 0 * 36);
#pragma unroll
                for (int u = 0; u < 8; u++) hv[u] = r4[u];
                DOT32R(p0, w0, hv);
                r4 = (const f4v*)(row + 1 * 36);
#pragma unroll
                for (int u = 0; u < 8; u++) hv[u] = r4[u];
                DOT32R(p1, w1, hv);
                r4 = (const f4v*)(row + 2 * 36);
#pragma unroll
                for (int u = 0; u < 8; u++) hv[u] = r4[u];
                DOT32R(p2, w2, hv);
                r4 = (const f4v*)(row + 3 * 36);
#pragma unroll
                for (int u = 0; u < 8; u++) hv[u] = r4[u];
                DOT32R(p3, w3, hv);
                float val = (p0 + p1) + (p2 + p3) + bsx;
                ast_(pxb + (size_t)(t0 + tt) * 128 + h, val);
                sacc += val; qacc += val * val;
            }
        }
        __syncthreads();
        shbuf[tq * 128 + h] = sacc;
        shbuf[512 + tq * 128 + h] = qacc;
        __syncthreads();
        if (tq == 0) {
            float s = shbuf[h] + shbuf[128 + h] + shbuf[256 + h] + shbuf[384 + h];
            float qq = shbuf[512 + h] + shbuf[640 + h] + shbuf[768 + h] + shbuf[896 + h];
            float m = s * (1.f / T_);
            float v = qq * (1.f / T_) - m * m;
            ast_(mu_px + b * 128 + h, m);
            ast_(inv_px + b * 128 + h, rsqrtf(fmaxf(v, 0.f) + EPS_));
        }
        __syncthreads();   // drains vmcnt: px + stats visible
        if (tid == 0) __hip_atomic_store(flag_px + b, 1, __ATOMIC_RELEASE, __HIP_MEMORY_SCOPE_AGENT);
    } else if (wg < 160) {
        // ======== h3-stats rider: IN stats of layer-3 h, chunk-incremental ========
        const int b = wg - 144;
        const int h = tid & 127, st = tid >> 7;
        const float* hsrc = h_glob + ((size_t)3 * 16 + b) * T_ * 128;
        int* f3 = flag_h + 3 * 16 + b;
        float s = 0.f, q = 0.f;
        for (int k = 0; k < NCHUNK_; k++) {
            if (tid == 0) wait_ge_(f3, k + 1);
            __syncthreads();
#pragma unroll
            for (int j = 0; j < 4; j++) {
                int tt = st * 4 + j;
                float v = ald_(hsrc + (size_t)(k * C_ + tt) * 128 + h);
                s += v; q += v * v;
            }
        }
        shbuf[st * 128 + h] = s;
        shbuf[512 + st * 128 + h] = q;
        __syncthreads();
        if (st == 0) {
            float ss = shbuf[h] + shbuf[128 + h] + shbuf[256 + h] + shbuf[384 + h];
            float qq = shbuf[512 + h] + shbuf[640 + h] + shbuf[768 + h] + shbuf[896 + h];
            float m = ss * (1.f / T_);
            float v = qq * (1.f / T_) - m * m;
            ast_(mu_ln + b * 128 + h, m);
            ast_(inv_ln + b * 128 + h, rsqrtf(fmaxf(v, 0.f) + EPS_));
        }
        __syncthreads();   // drains vmcnt
        if (tid == 0) __hip_atomic_store(flag_ln + b, 1, __ATOMIC_RELEASE, __HIP_MEMORY_SCOPE_AGENT);
    } else if (wg < 224) {
        // ======== score/tail rider: blk in [0,64), b = blk>>2, qt = blk&3 ========
        const int blk = wg - 160;
        const int b = blk >> 2, qt = blk & 3;
        const int m0 = qt * 64;                  // t-row offset within batch
        if (tid == 0) { wait_ge_(flag_px + b, 1); wait_ge_(flag_ln + b, 1); }
        __syncthreads();                          // acquire L1-inv applied CU-wide
        if (tid < 128) {                          // stage norm factors (plain loads)
            smu[tid] = mu_px[b * 128 + tid];
            siv[tid] = inv_px[b * 128 + tid];
        }
        __syncthreads();

        const float* h3b = h_glob + ((size_t)3 * 16 + b) * T_ * 128;
        float* phg = h_glob;                      // ph aliases layer-0 h (all readers done)
        const int lr = tid >> 3, lc = (tid & 7) << 2;   // A staging
        const int nB = tid >> 2, k0B = (tid & 3) << 3;  // B staging
        const int tm = (tid >> 5) << 2, tn = (tid & 31) << 2;
        float acc[4][4] = {};
        const float* mup = mu_ln + b * 128;
        const float* ivp = inv_ln + b * 128;
        for (int kb = 0; kb < 128; kb += 32) {
            float4 av = *(const float4*)(h3b + (size_t)(m0 + lr) * 128 + kb + lc);
            float4 m4 = *(const float4*)(mup + kb + lc);
            float4 i4 = *(const float4*)(ivp + kb + lc);
            av.x = (av.x - m4.x) * i4.x; av.y = (av.y - m4.y) * i4.y;
            av.z = (av.z - m4.z) * i4.z; av.w = (av.w - m4.w) * i4.w;
            float4 bv0 = *(const float4*)(proj_h_w + (size_t)nB * 128 + kb + k0B);
            float4 bv1 = *(const float4*)(proj_h_w + (size_t)nB * 128 + kb + k0B + 4);
            __syncthreads();
            *(float4*)&sAs[lr][lc] = av;
            sBs[k0B + 0][nB] = bv0.x; sBs[k0B + 1][nB] = bv0.y;
            sBs[k0B + 2][nB] = bv0.z; sBs[k0B + 3][nB] = bv0.w;
            sBs[k0B + 4][nB] = bv1.x; sBs[k0B + 5][nB] = bv1.y;
            sBs[k0B + 6][nB] = bv1.z; sBs[k0B + 7][nB] = bv1.w;
            __syncthreads();
#pragma unroll
            for (int k4 = 0; k4 < 8; k4++) {
                f4v a4[4];
#pragma unroll
                for (int i = 0; i < 4; i++) a4[i] = *(const f4v*)&sAs[tm + i][k4 * 4];
#pragma unroll
                for (int kk = 0; kk < 4; kk++) {
                    f4v b4 = *(const f4v*)&sBs[k4 * 4 + kk][tn];
#pragma unroll
                    for (int i = 0; i < 4; i++) {
                        acc[i][0] = fmaf(a4[i][kk], b4.x, acc[i][0]);
                        acc[i][1] = fmaf(a4[i][kk], b4.y, acc[i][1]);
                        acc[i][2] = fmaf(a4[i][kk], b4.z, acc[i][2]);
                        acc[i][3] = fmaf(a4[i][kk], b4.w, acc[i][3]);
                    }
                }
            }
        }
        // epilogue: ph + score partials (vectorized plain px read; LDS factors)
        float spart[4];
#pragma unroll
        for (int i = 0; i < 4; i++) {
            int t = m0 + tm + i;
            size_t prow = ((size_t)b * 256 + t) * 128;
            f4v pxv = *(const f4v*)(px + prow + tn);
            float sp = 0.f;
#pragma unroll
            for (int j = 0; j < 4; j++) {
                int col = tn + j;
                float val = acc[i][j] + proj_h_b[col];
                ast_(phg + prow + col, val);
                float inx = (pxv[j] - smu[col]) * siv[col];
                sp = fmaf(tanh_(val + inx), attn_w[col], sp);
            }
            spart[i] = sp;
        }
        __syncthreads();
#pragma unroll
        for (int i = 0; i < 4; i++) sred[tm + i][tid & 31] = spart[i];
        __syncthreads();
        if (tid < 64) {
            float s = 0.f;
#pragma unroll
            for (int j = 0; j < 32; j++) s += sred[tid][j];
            ast_(lsc + b * 256 + m0 + tid, s);
        }
        __syncthreads();   // drains vmcnt: ph + lsc visible
        if (tid == 0) {
            (void)__hip_atomic_fetch_add(cnt + b, 1, __ATOMIC_ACQ_REL, __HIP_MEMORY_SCOPE_AGENT);
            wait_ge_(cnt + b, 4);
        }
        __syncthreads();
        // softmax over lsc[b][0..255] (redundant per block, cheap; plain loads OK)
        float v = 0.f;
        if (tid < 256) { v = lsc[b * 256 + tid]; stmp[tid] = v; }
        __syncthreads();
        for (int off = 128; off > 0; off >>= 1) {
            if (tid < off) stmp[tid] = fmaxf(stmp[tid], stmp[tid + off]);
            __syncthreads();
        }
        float mx = stmp[0];
        __syncthreads();
        float e = (tid < 256) ? __expf(v - mx) : 0.f;
        if (tid < 256) stmp[tid] = e;
        __syncthreads();
        for (int off = 128; off > 0; off >>= 1) {
            if (tid < off) stmp[tid] += stmp[tid + off];
            __syncthreads();
        }
        float tot = stmp[0];
        __syncthreads();
        if (tid < 256) swsh[tid] = e / tot;
        __syncthreads();
        {   // attention-map quarter (alpha = softmax_t / D, constant across d)
            float* ob = out_att + (size_t)b * T_ * D_ + (size_t)m0 * 128;
            const float invD = 1.f / (float)D_;
            for (int i = tid; i < 64 * 128; i += 512)
                ob[i] = swsh[m0 + (i >> 7)] * invD;
        }
        if (qt == 0) {   // context + FC
            int h = tid & 127, st = tid >> 7;
            float a = 0.f;
            for (int tt = st * 64; tt < st * 64 + 64; tt++)
                a = fmaf(phg[((size_t)b * 256 + tt) * 128 + h], swsh[tt], a);
            sctx[st * 128 + h] = a;
            __syncthreads();
            if (tid < 128) sctx[tid] = sctx[tid] + sctx[128 + tid] + sctx[256 + tid] + sctx[384 + tid];
            __syncthreads();
            if (tid < NC_) {
                float s = fc_b[tid];
                const float* fw = fc_w + tid * 128;
                for (int k = 0; k < 128; k++) s = fmaf(sctx[k], fw[k], s);
                out[b * NC_ + tid] = s;
            }
        }
    } else {
        // ======== input-stats rider: b = wg - 224 ========
        const int b = wg - 224;
        const int d = tid & 127, r = tid >> 7;
        const float* xb = x + (size_t)b * T_ * 128;
        float s = 0.f, q = 0.f;
        for (int t = r; t < T_; t += 4) {
            float v = xb[(size_t)t * 128 + d];
            s += v; q += v * v;
        }
        shbuf[tid] = s; shbuf[512 + tid] = q;
        __syncthreads();
        if (r == 0) {
            s = shbuf[d] + shbuf[128 + d] + shbuf[256 + d] + shbuf[384 + d];
            q = shbuf[512 + d] + shbuf[640 + d] + shbuf[768 + d] + shbuf[896 + d];
            ast_(psumB + b * 128 + d, s);
            ast_(psqB + b * 128 + d, q);
        }
        __syncthreads();   // drains vmcnt: partials visible
        if (tid == 0) {
            (void)__hip_atomic_fetch_add(cnt_s, 1, __ATOMIC_ACQ_REL, __HIP_MEMORY_SCOPE_AGENT);
            wait_ge_(cnt_s, 16);
        }
        __syncthreads();   // acquire L1-inv applied CU-wide
        if (tid < 128) {
            float S = 0.f, Q = 0.f, sb = 0.f, qb = 0.f;
            for (int bb = 0; bb < 16; bb++) {
                float ps = psumB[bb * 128 + tid];   // plain after acquire
                float pq = psqB[bb * 128 + tid];
                S += ps; Q += pq;
                if (bb == b) { sb = ps; qb = pq; }
            }
            float n = (float)(B_ * T_);
            float m = S / n;
            float varu = (Q - n * m * m) / (n - 1.f);
            float sd = sqrtf(fmaxf(varu, 0.f)) + EPS_;
            float mu = sb * (1.f / T_);
            float varT = qb * (1.f / T_) - mu * mu;
            ast_(mu_bd + b * 128 + tid, mu);
            ast_(invn + b * 128 + tid, rsqrtf(fmaxf(varT, 0.f) + EPS_ * sd * sd));
        }
        __syncthreads();   // drains vmcnt: factors visible
        if (tid == 0) __hip_atomic_store(flag_norm + b, 1, __ATOMIC_RELEASE, __HIP_MEMORY_SCOPE_AGENT);
    }
}

// ---------------- launcher ----------------
extern "C" void kernel_launch(void* const* d_in, const int* in_sizes, int n_in,
                              void* d_out, int out_size, void* d_ws, size_t ws_size,
                              hipStream_t stream) {
    const float* x        = (const float*)d_in[0];
    const float* Wih      = (const float*)d_in[1];
    const float* Whh      = (const float*)d_in[2];
    const float* bih      = (const float*)d_in[3];
    const float* bhh      = (const float*)d_in[4];
    const float* proj_h_w = (const float*)d_in[5];
    const float* proj_h_b = (const float*)d_in[6];
    const float* proj_x_w = (const float*)d_in[7];
    const float* proj_x_b = (const float*)d_in[8];
    const float* attn_w   = (const float*)d_in[9];
    const float* fc_w     = (const float*)d_in[10];
    const float* fc_b     = (const float*)d_in[11];
    float* out = (float*)d_out;

    float* ws = (float*)d_ws;
    const size_t NTD = (size_t)B_ * T_ * D_;       // 524288
    float* h_glob = ws;                            // 4*NTD
    float* ring   = h_glob + 4 * NTD;              // 4*NTD
    float* px     = ring + 4 * NTD;                // 1*NTD
    float* smalls = px + NTD;
    float* psumB  = smalls;                        // 16*128
    float* psqB   = psumB + 2048;                  // 16*128
    float* mu_bd  = psqB + 2048;
    float* invn   = mu_bd + 2048;
    float* mu_ln  = invn + 2048;
    float* inv_ln = mu_ln + 2048;
    float* mu_px  = inv_ln + 2048;
    float* inv_px = mu_px + 2048;
    float* lsc    = inv_px + 2048;
    int*   flags  = (int*)(lsc + 4096);
    int*   flag_h   = flags;                       // [64]
    int*   flag_g   = flags + 64;                  // [64]
    int*   flag_px  = flags + 128;                 // [16]
    int*   flag_ln  = flags + 144;                 // [16]
    int*   cnt      = flags + 160;                 // [16]
    int*   flag_norm= flags + 176;                 // [16]
    int*   cnt_s    = flags + 192;                 // [1]

    hipMemsetAsync((void*)flags, 0, 256 * sizeof(int), stream);

    // single fused dispatch: stats + 4-layer LSTM pipeline + all riders + tail
    megascan<<<240, 512, 0, stream>>>(x, Wih, Whh, bih, bhh,
                                      proj_x_w, proj_x_b, proj_h_w, proj_h_b,
                                      attn_w, fc_w, fc_b,
                                      mu_bd, invn, psumB, psqB,
                                      h_glob, ring, px,
                                      mu_px, inv_px, mu_ln, inv_ln,
                                      lsc, out, out + B_ * NC_,
                                      flag_h, flag_g, flag_px, flag_ln, cnt,
                                      flag_norm, cnt_s);
}